// Round 1
// baseline (159.116 us; speedup 1.0000x reference)
//
#include <hip/hip_runtime.h>
#include <stdint.h>

typedef __attribute__((ext_vector_type(8))) short bf16x8;
typedef __attribute__((ext_vector_type(4))) float f32x4;
typedef __attribute__((ext_vector_type(4))) unsigned short u16x4;

// byte offset of the 16B block holding logical (row, col) in a [R][64]-bf16 swizzled tile
#define LDS_SWZ(row, col) (((((col) >> 3) ^ ((row) & 7)) << 4))

__device__ __forceinline__ unsigned short f2bf(float f) {
  union { float f; unsigned u; } v; v.f = f;
  unsigned r = v.u + 0x7FFFu + ((v.u >> 16) & 1u);
  return (unsigned short)(r >> 16);
}
__device__ __forceinline__ float bf2f(unsigned short h) {
  union { unsigned u; float f; } v; v.u = ((unsigned)h) << 16;
  return v.f;
}
__device__ __forceinline__ void gld_lds16(const void* g, void* l) {
  __builtin_amdgcn_global_load_lds((const __attribute__((address_space(1))) void*)g,
                                   (__attribute__((address_space(3))) void*)l, 16, 0, 0);
}

// ---------------- prep: fp32 -> bf16 casts ----------------
__global__ void k_prep(const float* __restrict__ x, const float* __restrict__ wq,
                       const float* __restrict__ wk, const float* __restrict__ wv,
                       const float* __restrict__ wr,
                       unsigned short* __restrict__ xb, unsigned short* __restrict__ wb,
                       unsigned short* __restrict__ wrb) {
  int q = blockIdx.x * blockDim.x + threadIdx.x;
  const float* src; unsigned short* dst; int off;
  if (q < 524288)      { src = x;  dst = xb;          off = q; }
  else if (q < 589824) { src = wq; dst = wb;          off = q - 524288; }
  else if (q < 655360) { src = wk; dst = wb + 262144; off = q - 589824; }
  else if (q < 720896) { src = wv; dst = wb + 524288; off = q - 655360; }
  else if (q < 749568) { src = wr; dst = wrb;         off = q - 720896; }
  else return;
  float4 v = ((const float4*)src)[off];
  u16x4 o; o.x = f2bf(v.x); o.y = f2bf(v.y); o.z = f2bf(v.z); o.w = f2bf(v.w);
  ((u16x4*)dst)[off] = o;
}

// Wsum[e][d] = sum_t Wo[e][t*64+d]  (exploits jnp.tile: final GEMM K=64)
__global__ void k_wsum(const float* __restrict__ wo, unsigned short* __restrict__ wsb) {
  int t = blockIdx.x * blockDim.x + threadIdx.x;
  if (t >= 512 * 64) return;
  int e = t >> 6, d = t & 63;
  float s = 0.f;
#pragma unroll
  for (int q = 0; q < 8; ++q) s += wo[e * 512 + q * 64 + d];
  wsb[t] = f2bf(s);
}

// ---------------- QKV projection GEMM: 128x128 tile, BK=64 ----------------
__global__ __launch_bounds__(256) void k_qkv(
    const unsigned short* __restrict__ xb, const unsigned short* __restrict__ wb,
    const float* __restrict__ bq, const float* __restrict__ bk, const float* __restrict__ bv,
    unsigned short* __restrict__ qb, unsigned short* __restrict__ kb,
    unsigned short* __restrict__ vtb) {
  __shared__ alignas(16) unsigned char As[128 * 128];
  __shared__ alignas(16) unsigned char Bs[128 * 128];
  const int tid = threadIdx.x;
  const int wave = tid >> 6, lane = tid & 63;
  const int rowbase = blockIdx.x * 128;
  const int colbase = blockIdx.y * 128;
  const int z = blockIdx.z;
  const unsigned short* W = wb + z * 512 * 512;
  const float* bias = (z == 0) ? bq : ((z == 1) ? bk : bv);
  const int wr = wave >> 1, wc = wave & 1;
  f32x4 acc[4][4] = {};
  for (int kt = 0; kt < 8; ++kt) {
    __syncthreads();
#pragma unroll
    for (int i = 0; i < 4; ++i) {
      const int L = i * 256 + tid;
      const int row = L >> 3, pos = L & 7;
      gld_lds16(xb + (rowbase + row) * 512 + kt * 64 + ((pos ^ (row & 7)) << 3),
                As + (i * 256 + wave * 64) * 16);
      gld_lds16(W + (colbase + row) * 512 + kt * 64 + ((pos ^ (row & 7)) << 3),
                Bs + (i * 256 + wave * 64) * 16);
    }
    __syncthreads();
#pragma unroll
    for (int kc = 0; kc < 2; ++kc) {
      bf16x8 af[4], bfr[4];
#pragma unroll
      for (int mq = 0; mq < 4; ++mq) {
        const int row = wr * 64 + mq * 16 + (lane & 15);
        const int col = kc * 32 + ((lane >> 4) << 3);
        af[mq] = *(const bf16x8*)(As + row * 128 + LDS_SWZ(row, col));
      }
#pragma unroll
      for (int nq = 0; nq < 4; ++nq) {
        const int row = wc * 64 + nq * 16 + (lane & 15);
        const int col = kc * 32 + ((lane >> 4) << 3);
        bfr[nq] = *(const bf16x8*)(Bs + row * 128 + LDS_SWZ(row, col));
      }
#pragma unroll
      for (int mq = 0; mq < 4; ++mq)
#pragma unroll
        for (int nq = 0; nq < 4; ++nq)
          acc[mq][nq] = __builtin_amdgcn_mfma_f32_16x16x32_bf16(af[mq], bfr[nq], acc[mq][nq], 0, 0, 0);
    }
  }
  const float qs = 0.18033688011112043f;  // log2(e)/8, folds 1/sqrt(DH) + exp2 base change
#pragma unroll
  for (int mq = 0; mq < 4; ++mq)
#pragma unroll
    for (int nq = 0; nq < 4; ++nq)
#pragma unroll
      for (int r = 0; r < 4; ++r) {
        const int grow = rowbase + wr * 64 + mq * 16 + ((lane >> 4) << 2) + r;
        const int col = colbase + wc * 64 + nq * 16 + (lane & 15);
        float v = acc[mq][nq][r] + bias[col];
        const int b = grow >> 11, n = grow & 2047;
        const int h = col >> 6, dh = col & 63;
        if (z == 0)      qb[(((b << 3) + h) * 2048 + n) * 64 + dh] = f2bf(v * qs);
        else if (z == 1) kb[(((b << 3) + h) * 2048 + n) * 64 + dh] = f2bf(v);
        else             vtb[((((b << 3) + h) << 6) + dh) * 2048 + n] = f2bf(v);
      }
}

// ---------------- flash attention: 64 q-rows / block, online softmax ----------------
__global__ __launch_bounds__(256) void k_attn(
    const unsigned short* __restrict__ qb, const unsigned short* __restrict__ kb,
    const unsigned short* __restrict__ vtb, unsigned short* __restrict__ hob) {
  __shared__ alignas(16) unsigned char Ks[64 * 128];
  __shared__ alignas(16) unsigned char Vs[64 * 128];
  __shared__ alignas(16) unsigned char Ps[4][16 * 128];
  const int tid = threadIdx.x, wave = tid >> 6, lane = tid & 63;
  const int bh = blockIdx.x >> 5;
  const int qt = blockIdx.x & 31;
  const int n0 = qt * 64 + wave * 16;
  bf16x8 qf[2];
#pragma unroll
  for (int kc = 0; kc < 2; ++kc)
    qf[kc] = *(const bf16x8*)(qb + (bh * 2048 + n0 + (lane & 15)) * 64 + kc * 32 + ((lane >> 4) << 3));
  f32x4 oacc[4] = {};
  float mrun[4], lrun[4];
#pragma unroll
  for (int r = 0; r < 4; ++r) { mrun[r] = -1e30f; lrun[r] = 0.f; }
  for (int t = 0; t < 32; ++t) {
    __syncthreads();
#pragma unroll
    for (int i = 0; i < 2; ++i) {
      const int L = i * 256 + tid;
      const int row = L >> 3, pos = L & 7;
      gld_lds16(kb + (bh * 2048 + t * 64 + row) * 64 + ((pos ^ (row & 7)) << 3),
                Ks + (i * 256 + wave * 64) * 16);
      gld_lds16(vtb + (bh * 64 + row) * 2048 + t * 64 + ((pos ^ (row & 7)) << 3),
                Vs + (i * 256 + wave * 64) * 16);
    }
    __syncthreads();
    // S = Q K^T (in log2 units, scale folded into q)
    f32x4 s[4];
#pragma unroll
    for (int mc = 0; mc < 4; ++mc) {
      f32x4 zz = {};
#pragma unroll
      for (int kc = 0; kc < 2; ++kc) {
        const int row = mc * 16 + (lane & 15);
        const int col = kc * 32 + ((lane >> 4) << 3);
        bf16x8 kf = *(const bf16x8*)(Ks + row * 128 + LDS_SWZ(row, col));
        zz = __builtin_amdgcn_mfma_f32_16x16x32_bf16(qf[kc], kf, zz, 0, 0, 0);
      }
      s[mc] = zz;
    }
    float mnew[4], sc[4], rs[4], pl[4][4];
#pragma unroll
    for (int r = 0; r < 4; ++r) {
      float v = fmaxf(fmaxf(s[0][r], s[1][r]), fmaxf(s[2][r], s[3][r]));
#pragma unroll
      for (int off = 1; off < 16; off <<= 1) v = fmaxf(v, __shfl_xor(v, off));
      mnew[r] = fmaxf(mrun[r], v);
      sc[r] = exp2f(mrun[r] - mnew[r]);
    }
#pragma unroll
    for (int r = 0; r < 4; ++r) {
      float ps = 0.f;
#pragma unroll
      for (int mc = 0; mc < 4; ++mc) { float p = exp2f(s[mc][r] - mnew[r]); pl[mc][r] = p; ps += p; }
#pragma unroll
      for (int off = 1; off < 16; off <<= 1) ps += __shfl_xor(ps, off);
      rs[r] = ps;
    }
#pragma unroll
    for (int r = 0; r < 4; ++r) { lrun[r] = lrun[r] * sc[r] + rs[r]; mrun[r] = mnew[r]; }
#pragma unroll
    for (int c2 = 0; c2 < 4; ++c2) {
      f32x4 o = oacc[c2];
#pragma unroll
      for (int r = 0; r < 4; ++r) o[r] *= sc[r];
      oacc[c2] = o;
    }
    // write P (bf16) to wave-private swizzled LDS tile [16][64]
    unsigned char* pw = Ps[wave];
#pragma unroll
    for (int mc = 0; mc < 4; ++mc)
#pragma unroll
      for (int r = 0; r < 4; ++r) {
        const int row = ((lane >> 4) << 2) + r;
        const int col = mc * 16 + (lane & 15);
        *(unsigned short*)(pw + row * 128 + LDS_SWZ(row, col) + ((col & 7) << 1)) = f2bf(pl[mc][r]);
      }
    __syncthreads();
    // PV
    bf16x8 pa[2];
#pragma unroll
    for (int kc = 0; kc < 2; ++kc) {
      const int row = (lane & 15);
      const int col = kc * 32 + ((lane >> 4) << 3);
      pa[kc] = *(const bf16x8*)(pw + row * 128 + LDS_SWZ(row, col));
    }
#pragma unroll
    for (int c2 = 0; c2 < 4; ++c2) {
      f32x4 o = oacc[c2];
#pragma unroll
      for (int kc = 0; kc < 2; ++kc) {
        const int row = c2 * 16 + (lane & 15);
        const int col = kc * 32 + ((lane >> 4) << 3);
        bf16x8 vf = *(const bf16x8*)(Vs + row * 128 + LDS_SWZ(row, col));
        o = __builtin_amdgcn_mfma_f32_16x16x32_bf16(pa[kc], vf, o, 0, 0, 0);
      }
      oacc[c2] = o;
    }
  }
#pragma unroll
  for (int c2 = 0; c2 < 4; ++c2)
#pragma unroll
    for (int r = 0; r < 4; ++r) {
      const int n = n0 + ((lane >> 4) << 2) + r;
      const int dh = c2 * 16 + (lane & 15);
      hob[(bh * 2048 + n) * 64 + dh] = f2bf(oacc[c2][r] / lrun[r]);
    }
}

// ---------------- pair diffs: mean_n || hi @ Wr[p]^T - hj || ----------------
__global__ __launch_bounds__(256) void k_pair(const unsigned short* __restrict__ hob,
                                              const unsigned short* __restrict__ wrb,
                                              float* __restrict__ diffs) {
  __shared__ alignas(16) unsigned char Ws[64 * 128];
  __shared__ alignas(16) unsigned char Hj[64 * 128];
  __shared__ float red[4];
  const int tid = threadIdx.x, wave = tid >> 6, lane = tid & 63;
  const int b = blockIdx.x / 28, p = blockIdx.x % 28;
  int pp = p, ii = 0;
  while (pp >= 7 - ii) { pp -= 7 - ii; ii++; }
  const int i = ii, j = ii + 1 + pp;
#pragma unroll
  for (int is = 0; is < 2; ++is) {
    const int L = is * 256 + tid;
    const int row = L >> 3, pos = L & 7;
    gld_lds16(wrb + (p * 64 + row) * 64 + ((pos ^ (row & 7)) << 3), Ws + (is * 256 + wave * 64) * 16);
  }
  __syncthreads();
  bf16x8 wf[4][2];
#pragma unroll
  for (int c = 0; c < 4; ++c)
#pragma unroll
    for (int kc = 0; kc < 2; ++kc) {
      const int row = c * 16 + (lane & 15);
      const int col = kc * 32 + ((lane >> 4) << 3);
      wf[c][kc] = *(const bf16x8*)(Ws + row * 128 + LDS_SWZ(row, col));
    }
  const unsigned short* hib = hob + ((b * 8 + i) * 2048) * 64;
  const unsigned short* hjb = hob + ((b * 8 + j) * 2048) * 64;
  float wacc = 0.f;
  for (int t = 0; t < 32; ++t) {
    __syncthreads();
#pragma unroll
    for (int is = 0; is < 2; ++is) {
      const int L = is * 256 + tid;
      const int row = L >> 3, pos = L & 7;
      gld_lds16(hjb + (t * 64 + row) * 64 + ((pos ^ (row & 7)) << 3), Hj + (is * 256 + wave * 64) * 16);
    }
    __syncthreads();
    const int rbase = t * 64 + wave * 16;
    f32x4 ri[4] = {};
#pragma unroll
    for (int kc = 0; kc < 2; ++kc) {
      bf16x8 hf = *(const bf16x8*)(hib + (rbase + (lane & 15)) * 64 + kc * 32 + ((lane >> 4) << 3));
#pragma unroll
      for (int c = 0; c < 4; ++c)
        ri[c] = __builtin_amdgcn_mfma_f32_16x16x32_bf16(hf, wf[c][kc], ri[c], 0, 0, 0);
    }
#pragma unroll
    for (int r = 0; r < 4; ++r) {
      const int row = wave * 16 + ((lane >> 4) << 2) + r;
      float ss = 0.f;
#pragma unroll
      for (int c = 0; c < 4; ++c) {
        const int col = c * 16 + (lane & 15);
        float hv = bf2f(*(const unsigned short*)(Hj + (row & 63) * 128 + LDS_SWZ(row & 63, col) + ((col & 7) << 1)));
        float d = ri[c][r] - hv;
        ss += d * d;
      }
#pragma unroll
      for (int off = 1; off < 16; off <<= 1) ss += __shfl_xor(ss, off);
      if ((lane & 15) == 0) wacc += sqrtf(ss);
    }
  }
  float tot = __shfl(wacc, 0) + __shfl(wacc, 16) + __shfl(wacc, 32) + __shfl(wacc, 48);
  if (lane == 0) red[wave] = tot;
  __syncthreads();
  if (tid == 0) diffs[blockIdx.x] = (red[0] + red[1] + red[2] + red[3]) / 2048.f;
}

// ---------------- agreement -> consensus -> softmax weights ----------------
__global__ void k_weights(const float* __restrict__ diffs, const float* __restrict__ scal,
                          float* __restrict__ wts) {
  __shared__ float sc_s[2][28];
  __shared__ float filt[2][8];
  const int t = threadIdx.x;
  const float scale = scal[0];
  if (t < 56) {
    int b = t / 28, p = t % 28;
    sc_s[b][p] = expf(-diffs[t] * scale / 0.1f);
  }
  __syncthreads();
  if (t < 16) {
    int b = t / 8, h = t % 8;
    float cons = 0.f;
    for (int h2 = 0; h2 < 8; ++h2)
      if (h2 != h) {
        int i_ = h < h2 ? h : h2, j_ = h < h2 ? h2 : h;
        int p = i_ * (15 - i_) / 2 + (j_ - i_ - 1);
        cons += sc_s[b][p];
      }
    cons /= 7.f;
    filt[b][h] = (cons > 0.1f) ? cons : 0.f;
  }
  __syncthreads();
  if (t < 16) {
    int b = t / 8, h = t % 8;
    float m = -1e30f;
    for (int h2 = 0; h2 < 8; ++h2) m = fmaxf(m, filt[b][h2] + 1e-10f);
    float s = 0.f;
    for (int h2 = 0; h2 < 8; ++h2) s += expf(filt[b][h2] + 1e-10f - m);
    wts[t] = expf(filt[b][h] + 1e-10f - m) / s;
  }
}

// ---------------- agg = sum_h w[b,h] * head_out ----------------
__global__ void k_agg(const unsigned short* __restrict__ hob, const float* __restrict__ wts,
                      unsigned short* __restrict__ aggb) {
  int t = blockIdx.x * blockDim.x + threadIdx.x;
  if (t >= 4096 * 8) return;
  int r = t >> 3, dblk = t & 7;
  int b = r >> 11, n = r & 2047;
  float acc[8] = {};
#pragma unroll
  for (int h = 0; h < 8; ++h) {
    float w = wts[b * 8 + h];
    bf16x8 v = *(const bf16x8*)(hob + (((b * 8 + h) << 11) + n) * 64 + dblk * 8);
#pragma unroll
    for (int e = 0; e < 8; ++e) acc[e] += w * bf2f((unsigned short)v[e]);
  }
  bf16x8 o;
#pragma unroll
  for (int e = 0; e < 8; ++e) o[e] = (short)f2bf(acc[e]);
  *(bf16x8*)(aggb + r * 64 + dblk * 8) = o;
}

// ---------------- final: out = agg @ Wsum^T + bo (K=64) ----------------
__global__ __launch_bounds__(256) void k_out(const unsigned short* __restrict__ aggb,
                                             const unsigned short* __restrict__ wsb,
                                             const float* __restrict__ bo,
                                             float* __restrict__ out) {
  __shared__ alignas(16) unsigned char Ws[64 * 128];
  const int tid = threadIdx.x, wave = tid >> 6, lane = tid & 63;
  const int rowb = blockIdx.x * 64, colb = blockIdx.y * 64;
#pragma unroll
  for (int is = 0; is < 2; ++is) {
    const int L = is * 256 + tid;
    const int row = L >> 3, pos = L & 7;
    gld_lds16(wsb + (colb + row) * 64 + ((pos ^ (row & 7)) << 3), Ws + (is * 256 + wave * 64) * 16);
  }
  __syncthreads();
  bf16x8 af[2];
#pragma unroll
  for (int kc = 0; kc < 2; ++kc)
    af[kc] = *(const bf16x8*)(aggb + (rowb + wave * 16 + (lane & 15)) * 64 + kc * 32 + ((lane >> 4) << 3));
  f32x4 acc[4] = {};
#pragma unroll
  for (int c = 0; c < 4; ++c)
#pragma unroll
    for (int kc = 0; kc < 2; ++kc) {
      const int row = c * 16 + (lane & 15);
      const int col = kc * 32 + ((lane >> 4) << 3);
      bf16x8 wfr = *(const bf16x8*)(Ws + row * 128 + LDS_SWZ(row, col));
      acc[c] = __builtin_amdgcn_mfma_f32_16x16x32_bf16(af[kc], wfr, acc[c], 0, 0, 0);
    }
#pragma unroll
  for (int c = 0; c < 4; ++c)
#pragma unroll
    for (int r = 0; r < 4; ++r) {
      const int grow = rowb + wave * 16 + ((lane >> 4) << 2) + r;
      const int col = colb + c * 16 + (lane & 15);
      out[grow * 512 + col] = acc[c][r] + bo[col];
    }
}

extern "C" void kernel_launch(void* const* d_in, const int* in_sizes, int n_in,
                              void* d_out, int out_size, void* d_ws, size_t ws_size,
                              hipStream_t stream) {
  const float* x  = (const float*)d_in[0];
  const float* Wq = (const float*)d_in[1];
  const float* bq = (const float*)d_in[2];
  const float* Wk = (const float*)d_in[3];
  const float* bk = (const float*)d_in[4];
  const float* Wv = (const float*)d_in[5];
  const float* bv = (const float*)d_in[6];
  const float* Wo = (const float*)d_in[7];
  const float* bo = (const float*)d_in[8];
  const float* Wr = (const float*)d_in[9];
  const float* ascale = (const float*)d_in[10];
  float* out = (float*)d_out;

  char* ws = (char*)d_ws;
  unsigned short* xb   = (unsigned short*)(ws);                          // 4096x512 bf16
  unsigned short* qb   = (unsigned short*)(ws + (4u << 20));             // [bh][n][dh]
  unsigned short* kb   = (unsigned short*)(ws + (8u << 20));             // [bh][n][dh]
  unsigned short* vtb  = (unsigned short*)(ws + (12u << 20));            // [bh][dh][n]
  unsigned short* hob  = (unsigned short*)(ws + (16u << 20));            // [bh][n][dh]
  unsigned short* wb   = (unsigned short*)(ws + (20u << 20));            // 3x512x512
  unsigned short* wrb  = (unsigned short*)(ws + (20u << 20) + 3u * 512 * 512 * 2);
  unsigned short* wsb  = (unsigned short*)(ws + (20u << 20) + 3u * 512 * 512 * 2 + 28u * 64 * 64 * 2);
  unsigned short* aggb = (unsigned short*)(ws + (22u << 20));            // 4096x64
  float* diffs = (float*)(ws + (23u << 20));                             // 56
  float* wts   = (float*)(ws + (23u << 20) + 1024);                      // 16

  k_prep<<<2928, 256, 0, stream>>>(x, Wq, Wk, Wv, Wr, xb, wb, wrb);
  k_wsum<<<128, 256, 0, stream>>>(Wo, wsb);
  k_qkv<<<dim3(32, 4, 3), 256, 0, stream>>>(xb, wb, bq, bk, bv, qb, kb, vtb);
  k_attn<<<512, 256, 0, stream>>>(qb, kb, vtb, hob);
  k_pair<<<56, 256, 0, stream>>>(hob, wrb, diffs);
  k_weights<<<1, 64, 0, stream>>>(diffs, ascale, wts);
  k_agg<<<128, 256, 0, stream>>>(hob, wts, aggb);
  k_out<<<dim3(64, 8), 256, 0, stream>>>(aggb, wsb, bo, out);
}

// Round 2
// 100.250 us; speedup vs baseline: 1.5872x; 1.5872x over previous
//
#include <hip/hip_runtime.h>
#include <stdint.h>

typedef __attribute__((ext_vector_type(8))) short bf16x8;
typedef __attribute__((ext_vector_type(4))) float f32x4;
typedef __attribute__((ext_vector_type(4))) unsigned short u16x4;

// byte offset of the 16B block holding logical (row, col) in a [R][64]-bf16 swizzled tile
#define LDS_SWZ(row, col) (((((col) >> 3) ^ ((row) & 7)) << 4))

__device__ __forceinline__ unsigned short f2bf(float f) {
  union { float f; unsigned u; } v; v.f = f;
  unsigned r = v.u + 0x7FFFu + ((v.u >> 16) & 1u);
  return (unsigned short)(r >> 16);
}
__device__ __forceinline__ float bf2f(unsigned short h) {
  union { unsigned u; float f; } v; v.u = ((unsigned)h) << 16;
  return v.f;
}
__device__ __forceinline__ void gld_lds16(const void* g, void* l) {
  __builtin_amdgcn_global_load_lds((const __attribute__((address_space(1))) void*)g,
                                   (__attribute__((address_space(3))) void*)l, 16, 0, 0);
}

// ---------------- prep: fp32 -> bf16 casts + Wo column-sum ----------------
__global__ void k_prep(const float* __restrict__ x, const float* __restrict__ wq,
                       const float* __restrict__ wk, const float* __restrict__ wv,
                       const float* __restrict__ wr, const float* __restrict__ wo,
                       unsigned short* __restrict__ xb, unsigned short* __restrict__ wb,
                       unsigned short* __restrict__ wrb, unsigned short* __restrict__ wsb) {
  int q = blockIdx.x * blockDim.x + threadIdx.x;
  if (q >= 749568) {
    // Wsum[e][d] = sum_t Wo[e][t*64+d]  (exploits jnp.tile: final GEMM K=64)
    int t = q - 749568;
    if (t >= 512 * 64) return;
    int e = t >> 6, d = t & 63;
    float s = 0.f;
#pragma unroll
    for (int qq = 0; qq < 8; ++qq) s += wo[e * 512 + qq * 64 + d];
    wsb[t] = f2bf(s);
    return;
  }
  const float* src; unsigned short* dst; int off;
  if (q < 524288)      { src = x;  dst = xb;          off = q; }
  else if (q < 589824) { src = wq; dst = wb;          off = q - 524288; }
  else if (q < 655360) { src = wk; dst = wb + 262144; off = q - 589824; }
  else if (q < 720896) { src = wv; dst = wb + 524288; off = q - 655360; }
  else                 { src = wr; dst = wrb;         off = q - 720896; }
  float4 v = ((const float4*)src)[off];
  u16x4 o; o.x = f2bf(v.x); o.y = f2bf(v.y); o.z = f2bf(v.z); o.w = f2bf(v.w);
  ((u16x4*)dst)[off] = o;
}

// ---------------- QKV projection GEMM: 128x128 tile, BK=64, double-buffered ----------------
__global__ __launch_bounds__(256) void k_qkv(
    const unsigned short* __restrict__ xb, const unsigned short* __restrict__ wb,
    const float* __restrict__ bq, const float* __restrict__ bk, const float* __restrict__ bv,
    unsigned short* __restrict__ qb, unsigned short* __restrict__ kb,
    unsigned short* __restrict__ vtb) {
  __shared__ alignas(16) unsigned char As[2][128 * 128];
  __shared__ alignas(16) unsigned char Bs[2][128 * 128];
  const int tid = threadIdx.x;
  const int wave = tid >> 6, lane = tid & 63;
  const int rowbase = blockIdx.x * 128;
  const int colbase = blockIdx.y * 128;
  const int z = blockIdx.z;
  const unsigned short* W = wb + z * 512 * 512;
  const float* bias = (z == 0) ? bq : ((z == 1) ? bk : bv);
  const int wr = wave >> 1, wc = wave & 1;
  f32x4 acc[4][4] = {};

#define QKV_STAGE(buf, kt_)                                                          \
  do {                                                                               \
    _Pragma("unroll") for (int i_ = 0; i_ < 4; ++i_) {                               \
      const int L_ = i_ * 256 + tid;                                                 \
      const int row_ = L_ >> 3, pos_ = L_ & 7;                                       \
      gld_lds16(xb + (rowbase + row_) * 512 + (kt_) * 64 + ((pos_ ^ (row_ & 7)) << 3), \
                As[buf] + (i_ * 256 + wave * 64) * 16);                              \
      gld_lds16(W + (colbase + row_) * 512 + (kt_) * 64 + ((pos_ ^ (row_ & 7)) << 3),  \
                Bs[buf] + (i_ * 256 + wave * 64) * 16);                              \
    }                                                                                \
  } while (0)

  QKV_STAGE(0, 0);
  __syncthreads();
  for (int kt = 0; kt < 8; ++kt) {
    const int cur = kt & 1;
    if (kt < 7) QKV_STAGE(cur ^ 1, kt + 1);
#pragma unroll
    for (int kc = 0; kc < 2; ++kc) {
      bf16x8 af[4], bfr[4];
#pragma unroll
      for (int mq = 0; mq < 4; ++mq) {
        const int row = wr * 64 + mq * 16 + (lane & 15);
        const int col = kc * 32 + ((lane >> 4) << 3);
        af[mq] = *(const bf16x8*)(As[cur] + row * 128 + LDS_SWZ(row, col));
      }
#pragma unroll
      for (int nq = 0; nq < 4; ++nq) {
        const int row = wc * 64 + nq * 16 + (lane & 15);
        const int col = kc * 32 + ((lane >> 4) << 3);
        bfr[nq] = *(const bf16x8*)(Bs[cur] + row * 128 + LDS_SWZ(row, col));
      }
#pragma unroll
      for (int mq = 0; mq < 4; ++mq)
#pragma unroll
        for (int nq = 0; nq < 4; ++nq)
          acc[mq][nq] = __builtin_amdgcn_mfma_f32_16x16x32_bf16(af[mq], bfr[nq], acc[mq][nq], 0, 0, 0);
    }
    __syncthreads();
  }
  const float qs = 0.18033688011112043f;  // log2(e)/8, folds 1/sqrt(DH) + exp2 base change
#pragma unroll
  for (int mq = 0; mq < 4; ++mq)
#pragma unroll
    for (int nq = 0; nq < 4; ++nq)
#pragma unroll
      for (int r = 0; r < 4; ++r) {
        const int grow = rowbase + wr * 64 + mq * 16 + ((lane >> 4) << 2) + r;
        const int col = colbase + wc * 64 + nq * 16 + (lane & 15);
        float v = acc[mq][nq][r] + bias[col];
        const int b = grow >> 11, n = grow & 2047;
        const int h = col >> 6, dh = col & 63;
        if (z == 0)      qb[(((b << 3) + h) * 2048 + n) * 64 + dh] = f2bf(v * qs);
        else if (z == 1) kb[(((b << 3) + h) * 2048 + n) * 64 + dh] = f2bf(v);
        else             vtb[((((b << 3) + h) << 6) + dh) * 2048 + n] = f2bf(v);
      }
}

// ---------------- flash attention: 64 q-rows / block, online softmax ----------------
// 2-phase pipelined staging, 1 barrier/tile, defer-max rescale (THR=8 in log2 units)
__global__ __launch_bounds__(256) void k_attn(
    const unsigned short* __restrict__ qb, const unsigned short* __restrict__ kb,
    const unsigned short* __restrict__ vtb, unsigned short* __restrict__ hob) {
  __shared__ alignas(16) unsigned char Ks[2][64 * 128];
  __shared__ alignas(16) unsigned char Vs[2][64 * 128];
  __shared__ alignas(16) unsigned char Ps[4][16 * 128];
  const int tid = threadIdx.x, wave = tid >> 6, lane = tid & 63;
  const int bh = blockIdx.x >> 5;
  const int qt = blockIdx.x & 31;
  const int n0 = qt * 64 + wave * 16;
  const unsigned short* kbase = kb + bh * 2048 * 64;
  const unsigned short* vbase = vtb + bh * 64 * 2048;
  bf16x8 qf[2];
#pragma unroll
  for (int kc = 0; kc < 2; ++kc)
    qf[kc] = *(const bf16x8*)(qb + (bh * 2048 + n0 + (lane & 15)) * 64 + kc * 32 + ((lane >> 4) << 3));
  f32x4 oacc[4] = {};
  float mrun[4], lpart[4];
#pragma unroll
  for (int r = 0; r < 4; ++r) { mrun[r] = -1e30f; lpart[r] = 0.f; }

#define ATTN_STAGE(buf, t_)                                                        \
  do {                                                                             \
    _Pragma("unroll") for (int i_ = 0; i_ < 2; ++i_) {                             \
      const int L_ = i_ * 256 + tid;                                               \
      const int row_ = L_ >> 3, pos_ = L_ & 7;                                     \
      gld_lds16(kbase + ((t_) * 64 + row_) * 64 + ((pos_ ^ (row_ & 7)) << 3),      \
                Ks[buf] + (i_ * 256 + wave * 64) * 16);                            \
      gld_lds16(vbase + row_ * 2048 + (t_) * 64 + ((pos_ ^ (row_ & 7)) << 3),      \
                Vs[buf] + (i_ * 256 + wave * 64) * 16);                            \
    }                                                                              \
  } while (0)

  ATTN_STAGE(0, 0);
  __syncthreads();
  for (int t = 0; t < 32; ++t) {
    const int cur = t & 1;
    if (t < 31) ATTN_STAGE(cur ^ 1, t + 1);
    // S = Q K^T (in log2 units, scale folded into q)
    f32x4 s[4];
#pragma unroll
    for (int mc = 0; mc < 4; ++mc) {
      f32x4 zz = {};
#pragma unroll
      for (int kc = 0; kc < 2; ++kc) {
        const int row = mc * 16 + (lane & 15);
        const int col = kc * 32 + ((lane >> 4) << 3);
        bf16x8 kf = *(const bf16x8*)(Ks[cur] + row * 128 + LDS_SWZ(row, col));
        zz = __builtin_amdgcn_mfma_f32_16x16x32_bf16(qf[kc], kf, zz, 0, 0, 0);
      }
      s[mc] = zz;
    }
    // per-lane tile max; full row reduce + rescale only when max grows past THR
    float lm[4];
#pragma unroll
    for (int r = 0; r < 4; ++r)
      lm[r] = fmaxf(fmaxf(s[0][r], s[1][r]), fmaxf(s[2][r], s[3][r]));
    bool need = (lm[0] > mrun[0] + 8.f) | (lm[1] > mrun[1] + 8.f) |
                (lm[2] > mrun[2] + 8.f) | (lm[3] > mrun[3] + 8.f);
    if (__any(need)) {
      float sc[4];
#pragma unroll
      for (int r = 0; r < 4; ++r) {
        float v = lm[r];
#pragma unroll
        for (int off = 1; off < 16; off <<= 1) v = fmaxf(v, __shfl_xor(v, off));
        float mnew = fmaxf(mrun[r], v);
        sc[r] = exp2f(mrun[r] - mnew);
        mrun[r] = mnew;
        lpart[r] *= sc[r];
      }
#pragma unroll
      for (int c2 = 0; c2 < 4; ++c2) {
        f32x4 o = oacc[c2];
#pragma unroll
        for (int r = 0; r < 4; ++r) o[r] *= sc[r];
        oacc[c2] = o;
      }
    }
    float pl[4][4];
#pragma unroll
    for (int r = 0; r < 4; ++r) {
      float ps = 0.f;
#pragma unroll
      for (int mc = 0; mc < 4; ++mc) { float p = exp2f(s[mc][r] - mrun[r]); pl[mc][r] = p; ps += p; }
      lpart[r] += ps;  // per-lane partial; row-reduced once at the end
    }
    // write P (bf16) to wave-private swizzled LDS tile [16][64] (no barrier needed)
    unsigned char* pw = Ps[wave];
#pragma unroll
    for (int mc = 0; mc < 4; ++mc)
#pragma unroll
      for (int r = 0; r < 4; ++r) {
        const int row = ((lane >> 4) << 2) + r;
        const int col = mc * 16 + (lane & 15);
        *(unsigned short*)(pw + row * 128 + LDS_SWZ(row, col) + ((col & 7) << 1)) = f2bf(pl[mc][r]);
      }
    // PV
    bf16x8 pa[2];
#pragma unroll
    for (int kc = 0; kc < 2; ++kc) {
      const int row = (lane & 15);
      const int col = kc * 32 + ((lane >> 4) << 3);
      pa[kc] = *(const bf16x8*)(pw + row * 128 + LDS_SWZ(row, col));
    }
#pragma unroll
    for (int c2 = 0; c2 < 4; ++c2) {
      f32x4 o = oacc[c2];
#pragma unroll
      for (int kc = 0; kc < 2; ++kc) {
        const int row = c2 * 16 + (lane & 15);
        const int col = kc * 32 + ((lane >> 4) << 3);
        bf16x8 vf = *(const bf16x8*)(Vs[cur] + row * 128 + LDS_SWZ(row, col));
        o = __builtin_amdgcn_mfma_f32_16x16x32_bf16(pa[kc], vf, o, 0, 0, 0);
      }
      oacc[c2] = o;
    }
    __syncthreads();
  }
  float linv[4];
#pragma unroll
  for (int r = 0; r < 4; ++r) {
    float v = lpart[r];
#pragma unroll
    for (int off = 1; off < 16; off <<= 1) v += __shfl_xor(v, off);
    linv[r] = 1.f / v;
  }
#pragma unroll
  for (int c2 = 0; c2 < 4; ++c2)
#pragma unroll
    for (int r = 0; r < 4; ++r) {
      const int n = n0 + ((lane >> 4) << 2) + r;
      const int dh = c2 * 16 + (lane & 15);
      hob[(bh * 2048 + n) * 64 + dh] = f2bf(oacc[c2][r] * linv[r]);
    }
}

// ---------------- pair diffs: partial sums of || hi @ Wr[p]^T - hj || over 512-row chunks ----------------
__global__ __launch_bounds__(256) void k_pair(const unsigned short* __restrict__ hob,
                                              const unsigned short* __restrict__ wrb,
                                              float* __restrict__ dpart) {
  __shared__ alignas(16) unsigned char Ws[64 * 128];
  __shared__ alignas(16) unsigned char Hj[2][64 * 128];
  __shared__ float red[4];
  const int tid = threadIdx.x, wave = tid >> 6, lane = tid & 63;
  const int chunk = blockIdx.x & 3, bp = blockIdx.x >> 2;
  const int b = bp / 28, p = bp % 28;
  int pp = p, ii = 0;
  while (pp >= 7 - ii) { pp -= 7 - ii; ii++; }
  const int i = ii, j = ii + 1 + pp;
  const unsigned short* hib = hob + ((b * 8 + i) * 2048) * 64;
  const unsigned short* hjb = hob + ((b * 8 + j) * 2048) * 64;

#define PAIR_STAGE(buf, t_)                                                      \
  do {                                                                           \
    _Pragma("unroll") for (int is_ = 0; is_ < 2; ++is_) {                        \
      const int L_ = is_ * 256 + tid;                                            \
      const int row_ = L_ >> 3, pos_ = L_ & 7;                                   \
      gld_lds16(hjb + ((t_) * 64 + row_) * 64 + ((pos_ ^ (row_ & 7)) << 3),      \
                Hj[buf] + (is_ * 256 + wave * 64) * 16);                         \
    }                                                                            \
  } while (0)

#pragma unroll
  for (int is = 0; is < 2; ++is) {
    const int L = is * 256 + tid;
    const int row = L >> 3, pos = L & 7;
    gld_lds16(wrb + (p * 64 + row) * 64 + ((pos ^ (row & 7)) << 3), Ws + (is * 256 + wave * 64) * 16);
  }
  PAIR_STAGE(0, chunk * 8);
  __syncthreads();
  bf16x8 wf[4][2];
#pragma unroll
  for (int c = 0; c < 4; ++c)
#pragma unroll
    for (int kc = 0; kc < 2; ++kc) {
      const int row = c * 16 + (lane & 15);
      const int col = kc * 32 + ((lane >> 4) << 3);
      wf[c][kc] = *(const bf16x8*)(Ws + row * 128 + LDS_SWZ(row, col));
    }
  float wacc = 0.f;
  for (int t = 0; t < 8; ++t) {
    const int tt = chunk * 8 + t;
    const int cur = t & 1;
    if (t < 7) PAIR_STAGE(cur ^ 1, tt + 1);
    const int rbase = tt * 64 + wave * 16;
    f32x4 ri[4] = {};
#pragma unroll
    for (int kc = 0; kc < 2; ++kc) {
      bf16x8 hf = *(const bf16x8*)(hib + (rbase + (lane & 15)) * 64 + kc * 32 + ((lane >> 4) << 3));
#pragma unroll
      for (int c = 0; c < 4; ++c)
        ri[c] = __builtin_amdgcn_mfma_f32_16x16x32_bf16(hf, wf[c][kc], ri[c], 0, 0, 0);
    }
#pragma unroll
    for (int r = 0; r < 4; ++r) {
      const int row = wave * 16 + ((lane >> 4) << 2) + r;
      float ss = 0.f;
#pragma unroll
      for (int c = 0; c < 4; ++c) {
        const int col = c * 16 + (lane & 15);
        float hv = bf2f(*(const unsigned short*)(Hj[cur] + (row & 63) * 128 + LDS_SWZ(row & 63, col) + ((col & 7) << 1)));
        float d = ri[c][r] - hv;
        ss += d * d;
      }
#pragma unroll
      for (int off = 1; off < 16; off <<= 1) ss += __shfl_xor(ss, off);
      if ((lane & 15) == 0) wacc += sqrtf(ss);
    }
    __syncthreads();
  }
  float tot = __shfl(wacc, 0) + __shfl(wacc, 16) + __shfl(wacc, 32) + __shfl(wacc, 48);
  if (lane == 0) red[wave] = tot;
  __syncthreads();
  if (tid == 0) dpart[blockIdx.x] = red[0] + red[1] + red[2] + red[3];
}

// ---------------- agg = sum_h w[b,h] * head_out  (weights computed inline) ----------------
__global__ __launch_bounds__(256) void k_agg(const unsigned short* __restrict__ hob,
                                             const float* __restrict__ dpart,
                                             const float* __restrict__ scal,
                                             unsigned short* __restrict__ aggb) {
  __shared__ float sc_s[2][28];
  __shared__ float filt[2][8];
  __shared__ float wts_s[16];
  const int tid = threadIdx.x;
  if (tid < 56) {
    int bb = tid / 28, pp = tid % 28;
    int base = (bb * 28 + pp) * 4;
    float diff = (dpart[base] + dpart[base + 1] + dpart[base + 2] + dpart[base + 3]) / 2048.f;
    sc_s[bb][pp] = expf(-diff * scal[0] / 0.1f);
  }
  __syncthreads();
  if (tid < 16) {
    int bb = tid / 8, h = tid % 8;
    float cons = 0.f;
    for (int h2 = 0; h2 < 8; ++h2)
      if (h2 != h) {
        int i_ = h < h2 ? h : h2, j_ = h < h2 ? h2 : h;
        int pp = i_ * (15 - i_) / 2 + (j_ - i_ - 1);
        cons += sc_s[bb][pp];
      }
    cons /= 7.f;
    filt[bb][h] = (cons > 0.1f) ? cons : 0.f;
  }
  __syncthreads();
  if (tid < 16) {
    int bb = tid / 8, h = tid % 8;
    float m = -1e30f;
    for (int h2 = 0; h2 < 8; ++h2) m = fmaxf(m, filt[bb][h2] + 1e-10f);
    float s = 0.f;
    for (int h2 = 0; h2 < 8; ++h2) s += expf(filt[bb][h2] + 1e-10f - m);
    wts_s[tid] = expf(filt[bb][h] + 1e-10f - m) / s;
  }
  __syncthreads();
  int t = blockIdx.x * blockDim.x + tid;
  if (t >= 4096 * 8) return;
  int r = t >> 3, dblk = t & 7;
  int b = r >> 11, n = r & 2047;
  float acc[8] = {};
#pragma unroll
  for (int h = 0; h < 8; ++h) {
    float w = wts_s[b * 8 + h];
    bf16x8 v = *(const bf16x8*)(hob + (((b * 8 + h) << 11) + n) * 64 + dblk * 8);
#pragma unroll
    for (int e = 0; e < 8; ++e) acc[e] += w * bf2f((unsigned short)v[e]);
  }
  bf16x8 o;
#pragma unroll
  for (int e = 0; e < 8; ++e) o[e] = (short)f2bf(acc[e]);
  *(bf16x8*)(aggb + r * 64 + dblk * 8) = o;
}

// ---------------- final: out = agg @ Wsum^T + bo (K=64) ----------------
__global__ __launch_bounds__(256) void k_out(const unsigned short* __restrict__ aggb,
                                             const unsigned short* __restrict__ wsb,
                                             const float* __restrict__ bo,
                                             float* __restrict__ out) {
  __shared__ alignas(16) unsigned char Ws[64 * 128];
  const int tid = threadIdx.x, wave = tid >> 6, lane = tid & 63;
  const int rowb = blockIdx.x * 64, colb = blockIdx.y * 64;
#pragma unroll
  for (int is = 0; is < 2; ++is) {
    const int L = is * 256 + tid;
    const int row = L >> 3, pos = L & 7;
    gld_lds16(wsb + (colb + row) * 64 + ((pos ^ (row & 7)) << 3), Ws + (is * 256 + wave * 64) * 16);
  }
  __syncthreads();
  bf16x8 af[2];
#pragma unroll
  for (int kc = 0; kc < 2; ++kc)
    af[kc] = *(const bf16x8*)(aggb + (rowb + wave * 16 + (lane & 15)) * 64 + kc * 32 + ((lane >> 4) << 3));
  f32x4 acc[4] = {};
#pragma unroll
  for (int c = 0; c < 4; ++c)
#pragma unroll
    for (int kc = 0; kc < 2; ++kc) {
      const int row = c * 16 + (lane & 15);
      const int col = kc * 32 + ((lane >> 4) << 3);
      bf16x8 wfr = *(const bf16x8*)(Ws + row * 128 + LDS_SWZ(row, col));
      acc[c] = __builtin_amdgcn_mfma_f32_16x16x32_bf16(af[kc], wfr, acc[c], 0, 0, 0);
    }
#pragma unroll
  for (int c = 0; c < 4; ++c)
#pragma unroll
    for (int r = 0; r < 4; ++r) {
      const int grow = rowb + wave * 16 + ((lane >> 4) << 2) + r;
      const int col = colb + c * 16 + (lane & 15);
      out[grow * 512 + col] = acc[c][r] + bo[col];
    }
}

extern "C" void kernel_launch(void* const* d_in, const int* in_sizes, int n_in,
                              void* d_out, int out_size, void* d_ws, size_t ws_size,
                              hipStream_t stream) {
  const float* x  = (const float*)d_in[0];
  const float* Wq = (const float*)d_in[1];
  const float* bq = (const float*)d_in[2];
  const float* Wk = (const float*)d_in[3];
  const float* bk = (const float*)d_in[4];
  const float* Wv = (const float*)d_in[5];
  const float* bv = (const float*)d_in[6];
  const float* Wo = (const float*)d_in[7];
  const float* bo = (const float*)d_in[8];
  const float* Wr = (const float*)d_in[9];
  const float* ascale = (const float*)d_in[10];
  float* out = (float*)d_out;

  char* ws = (char*)d_ws;
  unsigned short* xb   = (unsigned short*)(ws);                          // 4096x512 bf16
  unsigned short* qb   = (unsigned short*)(ws + (4u << 20));             // [bh][n][dh]
  unsigned short* kb   = (unsigned short*)(ws + (8u << 20));             // [bh][n][dh]
  unsigned short* vtb  = (unsigned short*)(ws + (12u << 20));            // [bh][dh][n]
  unsigned short* hob  = (unsigned short*)(ws + (16u << 20));            // [bh][n][dh]
  unsigned short* wb   = (unsigned short*)(ws + (20u << 20));            // 3x512x512
  unsigned short* wrb  = (unsigned short*)(ws + (20u << 20) + 3u * 512 * 512 * 2);
  unsigned short* wsb  = (unsigned short*)(ws + (20u << 20) + 3u * 512 * 512 * 2 + 28u * 64 * 64 * 2);
  unsigned short* aggb = (unsigned short*)(ws + (22u << 20));            // 4096x64
  float* dpart = (float*)(ws + (23u << 20));                             // 224

  k_prep<<<3056, 256, 0, stream>>>(x, Wq, Wk, Wv, Wr, Wo, xb, wb, wrb, wsb);
  k_qkv<<<dim3(32, 4, 3), 256, 0, stream>>>(xb, wb, bq, bk, bv, qb, kb, vtb);
  k_attn<<<512, 256, 0, stream>>>(qb, kb, vtb, hob);
  k_pair<<<224, 256, 0, stream>>>(hob, wrb, dpart);
  k_agg<<<128, 256, 0, stream>>>(hob, dpart, ascale, aggb);
  k_out<<<dim3(64, 8), 256, 0, stream>>>(aggb, wsb, bo, out);
}

// Round 4
// 83.033 us; speedup vs baseline: 1.9163x; 1.2074x over previous
//
#include <hip/hip_runtime.h>
#include <stdint.h>

typedef __attribute__((ext_vector_type(8))) short bf16x8;
typedef __attribute__((ext_vector_type(4))) float f32x4;
typedef __attribute__((ext_vector_type(4))) unsigned short u16x4;

// byte offset of the 16B block holding logical (row, col) in a [R][64]-bf16 swizzled tile
#define LDS_SWZ(row, col) (((((col) >> 3) ^ ((row) & 7)) << 4))

__device__ __forceinline__ unsigned short f2bf(float f) {
  union { float f; unsigned u; } v; v.f = f;
  unsigned r = v.u + 0x7FFFu + ((v.u >> 16) & 1u);
  return (unsigned short)(r >> 16);
}
__device__ __forceinline__ float bf2f(unsigned short h) {
  union { unsigned u; float f; } v; v.u = ((unsigned)h) << 16;
  return v.f;
}
__device__ __forceinline__ void gld_lds16(const void* g, void* l) {
  __builtin_amdgcn_global_load_lds((const __attribute__((address_space(1))) void*)g,
                                   (__attribute__((address_space(3))) void*)l, 16, 0, 0);
}

// ---------------- prep: fp32 -> bf16 casts + Wo column-sum ----------------
__global__ void k_prep(const float* __restrict__ x, const float* __restrict__ wq,
                       const float* __restrict__ wk, const float* __restrict__ wv,
                       const float* __restrict__ wr, const float* __restrict__ wo,
                       unsigned short* __restrict__ xb, unsigned short* __restrict__ wb,
                       unsigned short* __restrict__ wrb, unsigned short* __restrict__ wsb) {
  int q = blockIdx.x * blockDim.x + threadIdx.x;
  if (q >= 749568) {
    // Wsum[e][d] = sum_t Wo[e][t*64+d]  (exploits jnp.tile: final GEMM K=64)
    int t = q - 749568;
    if (t >= 512 * 64) return;
    int e = t >> 6, d = t & 63;
    float s = 0.f;
#pragma unroll
    for (int qq = 0; qq < 8; ++qq) s += wo[e * 512 + qq * 64 + d];
    wsb[t] = f2bf(s);
    return;
  }
  const float* src; unsigned short* dst; int off;
  if (q < 524288)      { src = x;  dst = xb;          off = q; }
  else if (q < 589824) { src = wq; dst = wb;          off = q - 524288; }
  else if (q < 655360) { src = wk; dst = wb + 262144; off = q - 589824; }
  else if (q < 720896) { src = wv; dst = wb + 524288; off = q - 655360; }
  else                 { src = wr; dst = wrb;         off = q - 720896; }
  float4 v = ((const float4*)src)[off];
  u16x4 o; o.x = f2bf(v.x); o.y = f2bf(v.y); o.z = f2bf(v.z); o.w = f2bf(v.w);
  ((u16x4*)dst)[off] = o;
}

// ---------------- QKV projection GEMM: 128x64 tile, BK=64, double-buffered ----------------
__global__ __launch_bounds__(256) void k_qkv(
    const unsigned short* __restrict__ xb, const unsigned short* __restrict__ wb,
    const float* __restrict__ bq, const float* __restrict__ bk, const float* __restrict__ bv,
    unsigned short* __restrict__ qb, unsigned short* __restrict__ kb,
    unsigned short* __restrict__ vtb) {
  __shared__ alignas(16) unsigned char As[2][128 * 128];
  __shared__ alignas(16) unsigned char Bs[2][64 * 128];
  const int tid = threadIdx.x;
  const int wave = tid >> 6, lane = tid & 63;
  const int rowbase = blockIdx.x * 128;
  const int colbase = blockIdx.y * 64;
  const int z = blockIdx.z;
  const unsigned short* W = wb + z * 512 * 512;
  const float* bias = (z == 0) ? bq : ((z == 1) ? bk : bv);
  f32x4 acc[2][4] = {};

#define QKV_STAGE(buf, kt_)                                                            \
  do {                                                                                 \
    _Pragma("unroll") for (int i_ = 0; i_ < 4; ++i_) {                                 \
      const int L_ = i_ * 256 + tid;                                                   \
      const int row_ = L_ >> 3, pos_ = L_ & 7;                                         \
      gld_lds16(xb + (rowbase + row_) * 512 + (kt_) * 64 + ((pos_ ^ (row_ & 7)) << 3), \
                As[buf] + (i_ * 256 + wave * 64) * 16);                                \
    }                                                                                  \
    _Pragma("unroll") for (int i_ = 0; i_ < 2; ++i_) {                                 \
      const int L_ = i_ * 256 + tid;                                                   \
      const int row_ = L_ >> 3, pos_ = L_ & 7;                                         \
      gld_lds16(W + (colbase + row_) * 512 + (kt_) * 64 + ((pos_ ^ (row_ & 7)) << 3),  \
                Bs[buf] + (i_ * 256 + wave * 64) * 16);                                \
    }                                                                                  \
  } while (0)

  QKV_STAGE(0, 0);
  __syncthreads();
  for (int kt = 0; kt < 8; ++kt) {
    const int cur = kt & 1;
    if (kt < 7) QKV_STAGE(cur ^ 1, kt + 1);
#pragma unroll
    for (int kc = 0; kc < 2; ++kc) {
      bf16x8 af[2], bfr[4];
#pragma unroll
      for (int mq = 0; mq < 2; ++mq) {
        const int row = wave * 32 + mq * 16 + (lane & 15);
        const int col = kc * 32 + ((lane >> 4) << 3);
        af[mq] = *(const bf16x8*)(As[cur] + row * 128 + LDS_SWZ(row, col));
      }
#pragma unroll
      for (int nq = 0; nq < 4; ++nq) {
        const int row = nq * 16 + (lane & 15);
        const int col = kc * 32 + ((lane >> 4) << 3);
        bfr[nq] = *(const bf16x8*)(Bs[cur] + row * 128 + LDS_SWZ(row, col));
      }
#pragma unroll
      for (int mq = 0; mq < 2; ++mq)
#pragma unroll
        for (int nq = 0; nq < 4; ++nq)
          acc[mq][nq] = __builtin_amdgcn_mfma_f32_16x16x32_bf16(af[mq], bfr[nq], acc[mq][nq], 0, 0, 0);
    }
    __syncthreads();
  }
  const float qs = 0.18033688011112043f;  // log2(e)/8, folds 1/sqrt(DH) + exp2 base change
#pragma unroll
  for (int mq = 0; mq < 2; ++mq)
#pragma unroll
    for (int nq = 0; nq < 4; ++nq)
#pragma unroll
      for (int r = 0; r < 4; ++r) {
        const int grow = rowbase + wave * 32 + mq * 16 + ((lane >> 4) << 2) + r;
        const int col = colbase + nq * 16 + (lane & 15);
        float v = acc[mq][nq][r] + bias[col];
        const int b = grow >> 11, n = grow & 2047;
        const int h = col >> 6, dh = col & 63;
        if (z == 0)      qb[(((b << 3) + h) * 2048 + n) * 64 + dh] = f2bf(v * qs);
        else if (z == 1) kb[(((b << 3) + h) * 2048 + n) * 64 + dh] = f2bf(v);
        else             vtb[((((b << 3) + h) << 6) + dh) * 2048 + n] = f2bf(v);
      }
}

// ---------------- flash attention: 64 q-rows / block, 8 waves = 2 KV-teams, in-block combine ----------------
// team 0 (waves 0-3): KV tiles 0-15; team 1 (waves 4-7): KV tiles 16-31.
// LDS: per-team K dbuf 16KB + V dbuf 16KB (=64KB) + Ps 8x2KB = 80KB -> 2 blocks/CU = 16 waves/CU.
__global__ __launch_bounds__(512, 4) void k_attn(
    const unsigned short* __restrict__ qb, const unsigned short* __restrict__ kb,
    const unsigned short* __restrict__ vtb, unsigned short* __restrict__ hob) {
  __shared__ alignas(16) unsigned char smem[81920];
  const int tid = threadIdx.x, wave = tid >> 6, lane = tid & 63;
  const int team = wave >> 2, w4 = wave & 3;
  const int ttid = tid & 255;
  const int bh = blockIdx.x >> 5;
  const int qt = blockIdx.x & 31;
  const int n0 = qt * 64 + w4 * 16;
  unsigned char* Kt = smem + team * 32768;
  unsigned char* Vt = Kt + 16384;
  unsigned char* pw = smem + 65536 + wave * 2048;
  const unsigned short* kbase = kb + bh * 2048 * 64;
  const unsigned short* vbase = vtb + bh * 64 * 2048;
  bf16x8 qf[2];
#pragma unroll
  for (int kc = 0; kc < 2; ++kc)
    qf[kc] = *(const bf16x8*)(qb + (bh * 2048 + n0 + (lane & 15)) * 64 + kc * 32 + ((lane >> 4) << 3));
  f32x4 oacc[4] = {};
  float mrun[4], lpart[4];
#pragma unroll
  for (int r = 0; r < 4; ++r) { mrun[r] = -1e30f; lpart[r] = 0.f; }

#define ATTN_STAGE(buf, T_)                                                        \
  do {                                                                             \
    _Pragma("unroll") for (int i_ = 0; i_ < 2; ++i_) {                             \
      const int L_ = i_ * 256 + ttid;                                              \
      const int row_ = L_ >> 3, pos_ = L_ & 7;                                     \
      gld_lds16(kbase + ((T_) * 64 + row_) * 64 + ((pos_ ^ (row_ & 7)) << 3),      \
                Kt + (buf) * 8192 + (i_ * 256 + w4 * 64) * 16);                    \
      gld_lds16(vbase + row_ * 2048 + (T_) * 64 + ((pos_ ^ (row_ & 7)) << 3),      \
                Vt + (buf) * 8192 + (i_ * 256 + w4 * 64) * 16);                    \
    }                                                                              \
  } while (0)

  ATTN_STAGE(0, team * 16);
  __syncthreads();
  for (int t = 0; t < 16; ++t) {
    const int cur = t & 1;
    if (t < 15) ATTN_STAGE(cur ^ 1, team * 16 + t + 1);
    // S = Q K^T (in log2 units, scale folded into q)
    f32x4 s[4];
#pragma unroll
    for (int mc = 0; mc < 4; ++mc) {
      f32x4 zz = {};
#pragma unroll
      for (int kc = 0; kc < 2; ++kc) {
        const int row = mc * 16 + (lane & 15);
        const int col = kc * 32 + ((lane >> 4) << 3);
        bf16x8 kf = *(const bf16x8*)(Kt + cur * 8192 + row * 128 + LDS_SWZ(row, col));
        zz = __builtin_amdgcn_mfma_f32_16x16x32_bf16(qf[kc], kf, zz, 0, 0, 0);
      }
      s[mc] = zz;
    }
    // per-lane tile max; full row reduce + rescale only when max grows past THR
    float lm[4];
#pragma unroll
    for (int r = 0; r < 4; ++r)
      lm[r] = fmaxf(fmaxf(s[0][r], s[1][r]), fmaxf(s[2][r], s[3][r]));
    bool need = (lm[0] > mrun[0] + 8.f) | (lm[1] > mrun[1] + 8.f) |
                (lm[2] > mrun[2] + 8.f) | (lm[3] > mrun[3] + 8.f);
    if (__any(need)) {
      float sc[4];
#pragma unroll
      for (int r = 0; r < 4; ++r) {
        float v = lm[r];
#pragma unroll
        for (int off = 1; off < 16; off <<= 1) v = fmaxf(v, __shfl_xor(v, off));
        float mnew = fmaxf(mrun[r], v);
        sc[r] = exp2f(mrun[r] - mnew);
        mrun[r] = mnew;
        lpart[r] *= sc[r];
      }
#pragma unroll
      for (int c2 = 0; c2 < 4; ++c2) {
        f32x4 o = oacc[c2];
#pragma unroll
        for (int r = 0; r < 4; ++r) o[r] *= sc[r];
        oacc[c2] = o;
      }
    }
    float pl[4][4];
#pragma unroll
    for (int r = 0; r < 4; ++r) {
      float ps = 0.f;
#pragma unroll
      for (int mc = 0; mc < 4; ++mc) { float p = exp2f(s[mc][r] - mrun[r]); pl[mc][r] = p; ps += p; }
      lpart[r] += ps;  // per-lane partial; row-reduced once at the end
    }
    // write P (bf16) to wave-private swizzled LDS tile [16][64] (no barrier needed)
#pragma unroll
    for (int mc = 0; mc < 4; ++mc)
#pragma unroll
      for (int r = 0; r < 4; ++r) {
        const int row = ((lane >> 4) << 2) + r;
        const int col = mc * 16 + (lane & 15);
        *(unsigned short*)(pw + row * 128 + LDS_SWZ(row, col) + ((col & 7) << 1)) = f2bf(pl[mc][r]);
      }
    // PV
    bf16x8 pa[2];
#pragma unroll
    for (int kc = 0; kc < 2; ++kc) {
      const int row = (lane & 15);
      const int col = kc * 32 + ((lane >> 4) << 3);
      pa[kc] = *(const bf16x8*)(pw + row * 128 + LDS_SWZ(row, col));
    }
#pragma unroll
    for (int c2 = 0; c2 < 4; ++c2) {
      f32x4 o = oacc[c2];
#pragma unroll
      for (int kc = 0; kc < 2; ++kc) {
        const int row = c2 * 16 + (lane & 15);
        const int col = kc * 32 + ((lane >> 4) << 3);
        bf16x8 vf = *(const bf16x8*)(Vt + cur * 8192 + row * 128 + LDS_SWZ(row, col));
        o = __builtin_amdgcn_mfma_f32_16x16x32_bf16(pa[kc], vf, o, 0, 0, 0);
      }
      oacc[c2] = o;
    }
    __syncthreads();
  }
  // ---- in-block combine of the two teams' partials ----
  float lsum[4];
#pragma unroll
  for (int r = 0; r < 4; ++r) {
    float v = lpart[r];
#pragma unroll
    for (int off = 1; off < 16; off <<= 1) v += __shfl_xor(v, off);
    lsum[r] = v;  // uniform within each 16-lane group (as is mrun)
  }
  float* ex = (float*)smem;  // reuse dead K/V area: [4 waves][64 lanes][24 floats] = 24.5KB
  float* p = ex + (w4 * 64 + lane) * 24;
  if (team == 1) {
#pragma unroll
    for (int c2 = 0; c2 < 4; ++c2)
#pragma unroll
      for (int r = 0; r < 4; ++r) p[c2 * 4 + r] = oacc[c2][r];
#pragma unroll
    for (int r = 0; r < 4; ++r) { p[16 + r] = mrun[r]; p[20 + r] = lsum[r]; }
  }
  __syncthreads();
  if (team == 0) {
    float m1[4], l1[4], w0[4], w1[4];
#pragma unroll
    for (int r = 0; r < 4; ++r) {
      m1[r] = p[16 + r]; l1[r] = p[20 + r];
      float ms = fmaxf(mrun[r], m1[r]);
      float a = exp2f(mrun[r] - ms), bq_ = exp2f(m1[r] - ms);
      float li = 1.f / (a * lsum[r] + bq_ * l1[r]);
      w0[r] = a * li; w1[r] = bq_ * li;
    }
#pragma unroll
    for (int c2 = 0; c2 < 4; ++c2)
#pragma unroll
      for (int r = 0; r < 4; ++r) {
        const int n = n0 + ((lane >> 4) << 2) + r;
        const int dh = c2 * 16 + (lane & 15);
        float o1 = p[c2 * 4 + r];
        hob[(bh * 2048 + n) * 64 + dh] = f2bf(w0[r] * oacc[c2][r] + w1[r] * o1);
      }
  }
}

// ---------------- pair diffs: partial sums of || hi @ Wr[p]^T - hj || over 256-row chunks ----------------
__global__ __launch_bounds__(256) void k_pair(const unsigned short* __restrict__ hob,
                                              const unsigned short* __restrict__ wrb,
                                              float* __restrict__ dpart) {
  __shared__ alignas(16) unsigned char Ws[64 * 128];
  __shared__ alignas(16) unsigned char Hj[2][64 * 128];
  __shared__ float red[4];
  const int tid = threadIdx.x, wave = tid >> 6, lane = tid & 63;
  const int chunk = blockIdx.x & 7, bp = blockIdx.x >> 3;
  const int b = bp / 28, p = bp % 28;
  int pp = p, ii = 0;
  while (pp >= 7 - ii) { pp -= 7 - ii; ii++; }
  const int i = ii, j = ii + 1 + pp;
  const unsigned short* hib = hob + ((b * 8 + i) * 2048) * 64;
  const unsigned short* hjb = hob + ((b * 8 + j) * 2048) * 64;

#define PAIR_STAGE(buf, t_)                                                      \
  do {                                                                           \
    _Pragma("unroll") for (int is_ = 0; is_ < 2; ++is_) {                        \
      const int L_ = is_ * 256 + tid;                                            \
      const int row_ = L_ >> 3, pos_ = L_ & 7;                                   \
      gld_lds16(hjb + ((t_) * 64 + row_) * 64 + ((pos_ ^ (row_ & 7)) << 3),      \
                Hj[buf] + (is_ * 256 + wave * 64) * 16);                         \
    }                                                                            \
  } while (0)

#pragma unroll
  for (int is = 0; is < 2; ++is) {
    const int L = is * 256 + tid;
    const int row = L >> 3, pos = L & 7;
    gld_lds16(wrb + (p * 64 + row) * 64 + ((pos ^ (row & 7)) << 3), Ws + (is * 256 + wave * 64) * 16);
  }
  PAIR_STAGE(0, chunk * 4);
  __syncthreads();
  bf16x8 wf[4][2];
#pragma unroll
  for (int c = 0; c < 4; ++c)
#pragma unroll
    for (int kc = 0; kc < 2; ++kc) {
      const int row = c * 16 + (lane & 15);
      const int col = kc * 32 + ((lane >> 4) << 3);
      wf[c][kc] = *(const bf16x8*)(Ws + row * 128 + LDS_SWZ(row, col));
    }
  float wacc = 0.f;
  for (int t = 0; t < 4; ++t) {
    const int tt = chunk * 4 + t;
    const int cur = t & 1;
    if (t < 3) PAIR_STAGE(cur ^ 1, tt + 1);
    const int rbase = tt * 64 + wave * 16;
    f32x4 ri[4] = {};
#pragma unroll
    for (int kc = 0; kc < 2; ++kc) {
      bf16x8 hf = *(const bf16x8*)(hib + (rbase + (lane & 15)) * 64 + kc * 32 + ((lane >> 4) << 3));
#pragma unroll
      for (int c = 0; c < 4; ++c)
        ri[c] = __builtin_amdgcn_mfma_f32_16x16x32_bf16(hf, wf[c][kc], ri[c], 0, 0, 0);
    }
#pragma unroll
    for (int r = 0; r < 4; ++r) {
      const int row = wave * 16 + ((lane >> 4) << 2) + r;
      float ss = 0.f;
#pragma unroll
      for (int c = 0; c < 4; ++c) {
        const int col = c * 16 + (lane & 15);
        float hv = bf2f(*(const unsigned short*)(Hj[cur] + (row & 63) * 128 + LDS_SWZ(row & 63, col) + ((col & 7) << 1)));
        float d = ri[c][r] - hv;
        ss += d * d;
      }
#pragma unroll
      for (int off = 1; off < 16; off <<= 1) ss += __shfl_xor(ss, off);
      if ((lane & 15) == 0) wacc += sqrtf(ss);
    }
    __syncthreads();
  }
  float tot = __shfl(wacc, 0) + __shfl(wacc, 16) + __shfl(wacc, 32) + __shfl(wacc, 48);
  if (lane == 0) red[wave] = tot;
  __syncthreads();
  if (tid == 0) dpart[blockIdx.x] = red[0] + red[1] + red[2] + red[3];
}

// ---------------- agg = sum_h w[b,h] * head_out  (weights computed inline) ----------------
__global__ __launch_bounds__(256) void k_agg(const unsigned short* __restrict__ hob,
                                             const float* __restrict__ dpart,
                                             const float* __restrict__ scal,
                                             unsigned short* __restrict__ aggb) {
  __shared__ float sc_s[2][28];
  __shared__ float filt[2][8];
  __shared__ float wts_s[16];
  const int tid = threadIdx.x;
  if (tid < 56) {
    int bb = tid / 28, pp = tid % 28;
    int base = (bb * 28 + pp) * 8;
    float diff = 0.f;
#pragma unroll
    for (int c = 0; c < 8; ++c) diff += dpart[base + c];
    diff /= 2048.f;
    sc_s[bb][pp] = expf(-diff * scal[0] / 0.1f);
  }
  __syncthreads();
  if (tid < 16) {
    int bb = tid / 8, h = tid % 8;
    float cons = 0.f;
    for (int h2 = 0; h2 < 8; ++h2)
      if (h2 != h) {
        int i_ = h < h2 ? h : h2, j_ = h < h2 ? h2 : h;
        int pp = i_ * (15 - i_) / 2 + (j_ - i_ - 1);
        cons += sc_s[bb][pp];
      }
    cons /= 7.f;
    filt[bb][h] = (cons > 0.1f) ? cons : 0.f;
  }
  __syncthreads();
  if (tid < 16) {
    int bb = tid / 8, h = tid % 8;
    float m = -1e30f;
    for (int h2 = 0; h2 < 8; ++h2) m = fmaxf(m, filt[bb][h2] + 1e-10f);
    float s = 0.f;
    for (int h2 = 0; h2 < 8; ++h2) s += expf(filt[bb][h2] + 1e-10f - m);
    wts_s[tid] = expf(filt[bb][h] + 1e-10f - m) / s;
  }
  __syncthreads();
  int t = blockIdx.x * blockDim.x + tid;
  if (t >= 4096 * 8) return;
  int r = t >> 3, dblk = t & 7;
  int b = r >> 11, n = r & 2047;
  float acc[8] = {};
#pragma unroll
  for (int h = 0; h < 8; ++h) {
    float w = wts_s[b * 8 + h];
    bf16x8 v = *(const bf16x8*)(hob + (((b * 8 + h) << 11) + n) * 64 + dblk * 8);
#pragma unroll
    for (int e = 0; e < 8; ++e) acc[e] += w * bf2f((unsigned short)v[e]);
  }
  bf16x8 o;
#pragma unroll
  for (int e = 0; e < 8; ++e) o[e] = (short)f2bf(acc[e]);
  *(bf16x8*)(aggb + r * 64 + dblk * 8) = o;
}

// ---------------- final: out = agg @ Wsum^T + bo (K=64) ----------------
__global__ __launch_bounds__(256) void k_out(const unsigned short* __restrict__ aggb,
                                             const unsigned short* __restrict__ wsb,
                                             const float* __restrict__ bo,
                                             float* __restrict__ out) {
  __shared__ alignas(16) unsigned char Ws[64 * 128];
  const int tid = threadIdx.x, wave = tid >> 6, lane = tid & 63;
  const int rowb = blockIdx.x * 64, colb = blockIdx.y * 64;
#pragma unroll
  for (int is = 0; is < 2; ++is) {
    const int L = is * 256 + tid;
    const int row = L >> 3, pos = L & 7;
    gld_lds16(wsb + (colb + row) * 64 + ((pos ^ (row & 7)) << 3), Ws + (is * 256 + wave * 64) * 16);
  }
  __syncthreads();
  bf16x8 af[2];
#pragma unroll
  for (int kc = 0; kc < 2; ++kc)
    af[kc] = *(const bf16x8*)(aggb + (rowb + wave * 16 + (lane & 15)) * 64 + kc * 32 + ((lane >> 4) << 3));
  f32x4 acc[4] = {};
#pragma unroll
  for (int c = 0; c < 4; ++c)
#pragma unroll
    for (int kc = 0; kc < 2; ++kc) {
      const int row = c * 16 + (lane & 15);
      const int col = kc * 32 + ((lane >> 4) << 3);
      bf16x8 wfr = *(const bf16x8*)(Ws + row * 128 + LDS_SWZ(row, col));
      acc[c] = __builtin_amdgcn_mfma_f32_16x16x32_bf16(af[kc], wfr, acc[c], 0, 0, 0);
    }
#pragma unroll
  for (int c = 0; c < 4; ++c)
#pragma unroll
    for (int r = 0; r < 4; ++r) {
      const int grow = rowb + wave * 16 + ((lane >> 4) << 2) + r;
      const int col = colb + c * 16 + (lane & 15);
      out[grow * 512 + col] = acc[c][r] + bo[col];
    }
}

extern "C" void kernel_launch(void* const* d_in, const int* in_sizes, int n_in,
                              void* d_out, int out_size, void* d_ws, size_t ws_size,
                              hipStream_t stream) {
  const float* x  = (const float*)d_in[0];
  const float* Wq = (const float*)d_in[1];
  const float* bq = (const float*)d_in[2];
  const float* Wk = (const float*)d_in[3];
  const float* bk = (const float*)d_in[4];
  const float* Wv = (const float*)d_in[5];
  const float* bv = (const float*)d_in[6];
  const float* Wo = (const float*)d_in[7];
  const float* bo = (const float*)d_in[8];
  const float* Wr = (const float*)d_in[9];
  const float* ascale = (const float*)d_in[10];
  float* out = (float*)d_out;

  // R2-proven layout: every big buffer at 4MB spacing.
  char* ws = (char*)d_ws;
  unsigned short* xb   = (unsigned short*)(ws);                          // 4096x512 bf16 (4MB)
  unsigned short* qb   = (unsigned short*)(ws + (4u << 20));             // [bh][n][dh] (4MB)
  unsigned short* kb   = (unsigned short*)(ws + (8u << 20));             // [bh][n][dh] (4MB)
  unsigned short* vtb  = (unsigned short*)(ws + (12u << 20));            // [bh][dh][n] (4MB)
  unsigned short* hob  = (unsigned short*)(ws + (16u << 20));            // [bh][n][dh] (4MB)
  unsigned short* wb   = (unsigned short*)(ws + (20u << 20));            // 3x512x512 (1.5MB)
  unsigned short* wrb  = (unsigned short*)(ws + (20u << 20) + 3u * 512 * 512 * 2);
  unsigned short* wsb  = (unsigned short*)(ws + (20u << 20) + 3u * 512 * 512 * 2 + 28u * 64 * 64 * 2);
  unsigned short* aggb = (unsigned short*)(ws + (22u << 20));            // 4096x64 (512KB)
  float* dpart = (float*)(ws + (23u << 20));                             // 448 floats

  k_prep<<<3056, 256, 0, stream>>>(x, Wq, Wk, Wv, Wr, Wo, xb, wb, wrb, wsb);
  k_qkv<<<dim3(32, 8, 3), 256, 0, stream>>>(xb, wb, bq, bk, bv, qb, kb, vtb);
  k_attn<<<512, 512, 0, stream>>>(qb, kb, vtb, hob);
  k_pair<<<448, 256, 0, stream>>>(hob, wrb, dpart);
  k_agg<<<128, 256, 0, stream>>>(hob, dpart, ascale, aggb);
  k_out<<<dim3(64, 8), 256, 0, stream>>>(aggb, wsb, bo, out);
}

// Round 5
// 78.777 us; speedup vs baseline: 2.0198x; 1.0540x over previous
//
#include <hip/hip_runtime.h>
#include <hip/hip_bf16.h>
#include <stdint.h>

typedef __attribute__((ext_vector_type(8))) short bf16x8;
typedef __attribute__((ext_vector_type(4))) float f32x4;
typedef __attribute__((ext_vector_type(4))) unsigned short u16x4;

// byte offset of the 16B block holding logical (row, col) in a [R][64]-bf16 swizzled tile
#define LDS_SWZ(row, col) (((((col) >> 3) ^ ((row) & 7)) << 4))

__device__ __forceinline__ unsigned short f2bf(float f) {
  union { float f; unsigned u; } v; v.f = f;
  unsigned r = v.u + 0x7FFFu + ((v.u >> 16) & 1u);
  return (unsigned short)(r >> 16);
}
__device__ __forceinline__ float bf2f(unsigned short h) {
  union { unsigned u; float f; } v; v.u = ((unsigned)h) << 16;
  return v.f;
}
// packed 2xf32 -> 2xbf16 (RNE); compiler lowers to v_cvt_pk_bf16_f32
__device__ __forceinline__ unsigned pk2bf(float a, float b) {
  __hip_bfloat162 h2 = __float22bfloat162_rn(float2{a, b});
  unsigned u; __builtin_memcpy(&u, &h2, 4); return u;
}
__device__ __forceinline__ void gld_lds16(const void* g, void* l) {
  __builtin_amdgcn_global_load_lds((const __attribute__((address_space(1))) void*)g,
                                   (__attribute__((address_space(3))) void*)l, 16, 0, 0);
}

// ---------------- prep: fp32 -> bf16 casts + Wo column-sum ----------------
__global__ void k_prep(const float* __restrict__ x, const float* __restrict__ wq,
                       const float* __restrict__ wk, const float* __restrict__ wv,
                       const float* __restrict__ wr, const float* __restrict__ wo,
                       unsigned short* __restrict__ xb, unsigned short* __restrict__ wb,
                       unsigned short* __restrict__ wrb, unsigned short* __restrict__ wsb) {
  int q = blockIdx.x * blockDim.x + threadIdx.x;
  if (q >= 749568) {
    // Wsum[e][d] = sum_t Wo[e][t*64+d]  (exploits jnp.tile: final GEMM K=64)
    int t = q - 749568;
    if (t >= 512 * 64) return;
    int e = t >> 6, d = t & 63;
    float s = 0.f;
#pragma unroll
    for (int qq = 0; qq < 8; ++qq) s += wo[e * 512 + qq * 64 + d];
    wsb[t] = f2bf(s);
    return;
  }
  const float* src; unsigned short* dst; int off;
  if (q < 524288)      { src = x;  dst = xb;          off = q; }
  else if (q < 589824) { src = wq; dst = wb;          off = q - 524288; }
  else if (q < 655360) { src = wk; dst = wb + 262144; off = q - 589824; }
  else if (q < 720896) { src = wv; dst = wb + 524288; off = q - 655360; }
  else                 { src = wr; dst = wrb;         off = q - 720896; }
  float4 v = ((const float4*)src)[off];
  u16x4 o; o.x = f2bf(v.x); o.y = f2bf(v.y); o.z = f2bf(v.z); o.w = f2bf(v.w);
  ((u16x4*)dst)[off] = o;
}

// ---------------- QKV projection GEMM: 128x64 tile, BK=64, double-buffered ----------------
__global__ __launch_bounds__(256) void k_qkv(
    const unsigned short* __restrict__ xb, const unsigned short* __restrict__ wb,
    const float* __restrict__ bq, const float* __restrict__ bk, const float* __restrict__ bv,
    unsigned short* __restrict__ qb, unsigned short* __restrict__ kb,
    unsigned short* __restrict__ vtb) {
  __shared__ alignas(16) unsigned char As[2][128 * 128];
  __shared__ alignas(16) unsigned char Bs[2][64 * 128];
  const int tid = threadIdx.x;
  const int wave = tid >> 6, lane = tid & 63;
  const int rowbase = blockIdx.x * 128;
  const int colbase = blockIdx.y * 64;
  const int z = blockIdx.z;
  const unsigned short* W = wb + z * 512 * 512;
  const float* bias = (z == 0) ? bq : ((z == 1) ? bk : bv);
  f32x4 acc[2][4] = {};

#define QKV_STAGE(buf, kt_)                                                            \
  do {                                                                                 \
    _Pragma("unroll") for (int i_ = 0; i_ < 4; ++i_) {                                 \
      const int L_ = i_ * 256 + tid;                                                   \
      const int row_ = L_ >> 3, pos_ = L_ & 7;                                         \
      gld_lds16(xb + (rowbase + row_) * 512 + (kt_) * 64 + ((pos_ ^ (row_ & 7)) << 3), \
                As[buf] + (i_ * 256 + wave * 64) * 16);                                \
    }                                                                                  \
    _Pragma("unroll") for (int i_ = 0; i_ < 2; ++i_) {                                 \
      const int L_ = i_ * 256 + tid;                                                   \
      const int row_ = L_ >> 3, pos_ = L_ & 7;                                         \
      gld_lds16(W + (colbase + row_) * 512 + (kt_) * 64 + ((pos_ ^ (row_ & 7)) << 3),  \
                Bs[buf] + (i_ * 256 + wave * 64) * 16);                                \
    }                                                                                  \
  } while (0)

  QKV_STAGE(0, 0);
  __syncthreads();
  for (int kt = 0; kt < 8; ++kt) {
    const int cur = kt & 1;
    if (kt < 7) QKV_STAGE(cur ^ 1, kt + 1);
#pragma unroll
    for (int kc = 0; kc < 2; ++kc) {
      bf16x8 af[2], bfr[4];
#pragma unroll
      for (int mq = 0; mq < 2; ++mq) {
        const int row = wave * 32 + mq * 16 + (lane & 15);
        const int col = kc * 32 + ((lane >> 4) << 3);
        af[mq] = *(const bf16x8*)(As[cur] + row * 128 + LDS_SWZ(row, col));
      }
#pragma unroll
      for (int nq = 0; nq < 4; ++nq) {
        const int row = nq * 16 + (lane & 15);
        const int col = kc * 32 + ((lane >> 4) << 3);
        bfr[nq] = *(const bf16x8*)(Bs[cur] + row * 128 + LDS_SWZ(row, col));
      }
#pragma unroll
      for (int mq = 0; mq < 2; ++mq)
#pragma unroll
        for (int nq = 0; nq < 4; ++nq)
          acc[mq][nq] = __builtin_amdgcn_mfma_f32_16x16x32_bf16(af[mq], bfr[nq], acc[mq][nq], 0, 0, 0);
    }
    __syncthreads();
  }
  const float qs = 0.18033688011112043f;  // log2(e)/8, folds 1/sqrt(DH) + exp2 base change
#pragma unroll
  for (int mq = 0; mq < 2; ++mq)
#pragma unroll
    for (int nq = 0; nq < 4; ++nq)
#pragma unroll
      for (int r = 0; r < 4; ++r) {
        const int grow = rowbase + wave * 32 + mq * 16 + ((lane >> 4) << 2) + r;
        const int col = colbase + nq * 16 + (lane & 15);
        float v = acc[mq][nq][r] + bias[col];
        const int b = grow >> 11, n = grow & 2047;
        const int h = col >> 6, dh = col & 63;
        if (z == 0)      qb[(((b << 3) + h) * 2048 + n) * 64 + dh] = f2bf(v * qs);
        else if (z == 1) kb[(((b << 3) + h) * 2048 + n) * 64 + dh] = f2bf(v);
        else             vtb[((((b << 3) + h) << 6) + dh) * 2048 + n] = f2bf(v);
      }
}

// ---------------- flash attention: 64 q-rows / block, 8 waves = 2 KV-teams, in-block combine ----------------
// Swapped QK^T: S^T = mfma(K,Q) puts q = lane&15 -> softmax state is scalar per lane;
// P values are k-consecutive per lane -> packed cvt + ds_write_b64, no per-element f2bf.
__global__ __launch_bounds__(512, 4) void k_attn(
    const unsigned short* __restrict__ qb, const unsigned short* __restrict__ kb,
    const unsigned short* __restrict__ vtb, unsigned short* __restrict__ hob) {
  __shared__ alignas(16) unsigned char smem[81920];
  const int tid = threadIdx.x, wave = tid >> 6, lane = tid & 63;
  const int team = wave >> 2, w4 = wave & 3;
  const int ttid = tid & 255;
  const int bh = blockIdx.x >> 5;
  const int qt = blockIdx.x & 31;
  const int n0 = qt * 64 + w4 * 16;
  const int lq = lane & 15, lg = lane >> 4;
  unsigned char* Kt = smem + team * 32768;
  unsigned char* Vt = Kt + 16384;
  unsigned char* pw = smem + 65536 + wave * 2048;
  const unsigned short* kbase = kb + bh * 2048 * 64;
  const unsigned short* vbase = vtb + bh * 64 * 2048;
  bf16x8 qf[2];
#pragma unroll
  for (int kc = 0; kc < 2; ++kc)
    qf[kc] = *(const bf16x8*)(qb + (bh * 2048 + n0 + lq) * 64 + kc * 32 + (lg << 3));
  f32x4 oacc[4] = {};
  float mrun = -1e30f, lpart = 0.f;  // state for q-row = n0 + lq (replicated over 4 lane-groups)

#define ATTN_STAGE(buf, T_)                                                        \
  do {                                                                             \
    _Pragma("unroll") for (int i_ = 0; i_ < 2; ++i_) {                             \
      const int L_ = i_ * 256 + ttid;                                              \
      const int row_ = L_ >> 3, pos_ = L_ & 7;                                     \
      gld_lds16(kbase + ((T_) * 64 + row_) * 64 + ((pos_ ^ (row_ & 7)) << 3),      \
                Kt + (buf) * 8192 + (i_ * 256 + w4 * 64) * 16);                    \
      gld_lds16(vbase + row_ * 2048 + (T_) * 64 + ((pos_ ^ (row_ & 7)) << 3),      \
                Vt + (buf) * 8192 + (i_ * 256 + w4 * 64) * 16);                    \
    }                                                                              \
  } while (0)

  ATTN_STAGE(0, team * 16);
  __syncthreads();
  for (int t = 0; t < 16; ++t) {
    const int cur = t & 1;
    if (t < 15) ATTN_STAGE(cur ^ 1, team * 16 + t + 1);
    // S^T tile: s[mc] holds S[q = n0+lq][k = tile + mc*16 + lg*4 + r]
    f32x4 s[4];
#pragma unroll
    for (int mc = 0; mc < 4; ++mc) {
      f32x4 zz = {};
#pragma unroll
      for (int kc = 0; kc < 2; ++kc) {
        const int row = mc * 16 + lq;
        const int col = kc * 32 + (lg << 3);
        bf16x8 kf = *(const bf16x8*)(Kt + cur * 8192 + row * 128 + LDS_SWZ(row, col));
        zz = __builtin_amdgcn_mfma_f32_16x16x32_bf16(kf, qf[kc], zz, 0, 0, 0);
      }
      s[mc] = zz;
    }
    // in-lane max over this lane's 16 k's; rescale only when it grows past THR=8 (log2 units)
    float lm = s[0][0];
#pragma unroll
    for (int mc = 0; mc < 4; ++mc)
#pragma unroll
      for (int r = 0; r < 4; ++r) lm = fmaxf(lm, s[mc][r]);
    if (__any(lm > mrun + 8.f)) {
      float v = fmaxf(lm, __shfl_xor(lm, 16));
      v = fmaxf(v, __shfl_xor(v, 32));
      float mnew = fmaxf(mrun, v);
      float sc = exp2f(mrun - mnew);
      mrun = mnew; lpart *= sc;
      float sco[4];
#pragma unroll
      for (int r = 0; r < 4; ++r) sco[r] = __shfl(sc, (lane & 48) | ((lg << 2) + r));
#pragma unroll
      for (int c2 = 0; c2 < 4; ++c2) {
        f32x4 o = oacc[c2];
#pragma unroll
        for (int r = 0; r < 4; ++r) o[r] *= sco[r];
        oacc[c2] = o;
      }
    }
    // P = exp2(S - m), packed write: 4 k-consecutive values per mc -> one ds_write_b64
    float pl[4][4];
#pragma unroll
    for (int mc = 0; mc < 4; ++mc) {
      float ps = 0.f;
#pragma unroll
      for (int r = 0; r < 4; ++r) { float p = exp2f(s[mc][r] - mrun); pl[mc][r] = p; ps += p; }
      lpart += ps;
      const int kk = mc * 16 + (lg << 2);
      uint2 pkd = { pk2bf(pl[mc][0], pl[mc][1]), pk2bf(pl[mc][2], pl[mc][3]) };
      *(uint2*)(pw + lq * 128 + LDS_SWZ(lq, kk) + ((kk & 7) << 1)) = pkd;
    }
    // PV (wave-private P tile, no barrier needed)
    bf16x8 pa[2];
#pragma unroll
    for (int kc = 0; kc < 2; ++kc)
      pa[kc] = *(const bf16x8*)(pw + lq * 128 + LDS_SWZ(lq, kc * 32 + (lg << 3)));
#pragma unroll
    for (int c2 = 0; c2 < 4; ++c2) {
      f32x4 o = oacc[c2];
#pragma unroll
      for (int kc = 0; kc < 2; ++kc) {
        const int row = c2 * 16 + lq;
        const int col = kc * 32 + (lg << 3);
        bf16x8 vf = *(const bf16x8*)(Vt + cur * 8192 + row * 128 + LDS_SWZ(row, col));
        o = __builtin_amdgcn_mfma_f32_16x16x32_bf16(pa[kc], vf, o, 0, 0, 0);
      }
      oacc[c2] = o;
    }
    __syncthreads();
  }
  // reduce l across the 4 lane-groups (per q = lq)
  float ltot = lpart + __shfl_xor(lpart, 16);
  ltot += __shfl_xor(ltot, 32);
  // re-index m,l to the accumulator's row mapping q_o = lg*4 + r
  float m_o[4], l_o[4];
#pragma unroll
  for (int r = 0; r < 4; ++r) {
    const int src = (lane & 48) | ((lg << 2) + r);
    m_o[r] = __shfl(mrun, src);
    l_o[r] = __shfl(ltot, src);
  }
  // ---- in-block combine of the two teams' partials (stride 25 floats: conflict-free) ----
  float* ex = (float*)smem;  // reuse dead K/V area: [4 waves][64 lanes][25 floats] = 25.6KB
  float* px = ex + (w4 * 64 + lane) * 25;
  if (team == 1) {
#pragma unroll
    for (int c2 = 0; c2 < 4; ++c2)
#pragma unroll
      for (int r = 0; r < 4; ++r) px[c2 * 4 + r] = oacc[c2][r];
#pragma unroll
    for (int r = 0; r < 4; ++r) { px[16 + r] = m_o[r]; px[20 + r] = l_o[r]; }
  }
  __syncthreads();
  if (team == 0) {
    float w0[4], w1[4];
#pragma unroll
    for (int r = 0; r < 4; ++r) {
      float m1 = px[16 + r], l1 = px[20 + r];
      float ms = fmaxf(m_o[r], m1);
      float a = exp2f(m_o[r] - ms), b = exp2f(m1 - ms);
      float li = 1.f / (a * l_o[r] + b * l1);
      w0[r] = a * li; w1[r] = b * li;
    }
#pragma unroll
    for (int c2 = 0; c2 < 4; ++c2)
#pragma unroll
      for (int r = 0; r < 4; ++r) {
        const int n = n0 + (lg << 2) + r;
        const int dh = c2 * 16 + lq;
        float o1 = px[c2 * 4 + r];
        hob[(bh * 2048 + n) * 64 + dh] = f2bf(w0[r] * oacc[c2][r] + w1[r] * o1);
      }
  }
}

// ---------------- pair diffs: partial sums of || hi @ Wr[p]^T - hj || over 256-row chunks ----------------
__global__ __launch_bounds__(256) void k_pair(const unsigned short* __restrict__ hob,
                                              const unsigned short* __restrict__ wrb,
                                              float* __restrict__ dpart) {
  __shared__ alignas(16) unsigned char Ws[64 * 128];
  __shared__ alignas(16) unsigned char Hj[2][64 * 128];
  __shared__ float red[4];
  const int tid = threadIdx.x, wave = tid >> 6, lane = tid & 63;
  const int chunk = blockIdx.x & 7, bp = blockIdx.x >> 3;
  const int b = bp / 28, p = bp % 28;
  int pp = p, ii = 0;
  while (pp >= 7 - ii) { pp -= 7 - ii; ii++; }
  const int i = ii, j = ii + 1 + pp;
  const unsigned short* hib = hob + ((b * 8 + i) * 2048) * 64;
  const unsigned short* hjb = hob + ((b * 8 + j) * 2048) * 64;

#define PAIR_STAGE(buf, t_)                                                      \
  do {                                                                           \
    _Pragma("unroll") for (int is_ = 0; is_ < 2; ++is_) {                        \
      const int L_ = is_ * 256 + tid;                                            \
      const int row_ = L_ >> 3, pos_ = L_ & 7;                                   \
      gld_lds16(hjb + ((t_) * 64 + row_) * 64 + ((pos_ ^ (row_ & 7)) << 3),      \
                Hj[buf] + (is_ * 256 + wave * 64) * 16);                         \
    }                                                                            \
  } while (0)

#pragma unroll
  for (int is = 0; is < 2; ++is) {
    const int L = is * 256 + tid;
    const int row = L >> 3, pos = L & 7;
    gld_lds16(wrb + (p * 64 + row) * 64 + ((pos ^ (row & 7)) << 3), Ws + (is * 256 + wave * 64) * 16);
  }
  PAIR_STAGE(0, chunk * 4);
  __syncthreads();
  bf16x8 wf[4][2];
#pragma unroll
  for (int c = 0; c < 4; ++c)
#pragma unroll
    for (int kc = 0; kc < 2; ++kc) {
      const int row = c * 16 + (lane & 15);
      const int col = kc * 32 + ((lane >> 4) << 3);
      wf[c][kc] = *(const bf16x8*)(Ws + row * 128 + LDS_SWZ(row, col));
    }
  float wacc = 0.f;
  for (int t = 0; t < 4; ++t) {
    const int tt = chunk * 4 + t;
    const int cur = t & 1;
    if (t < 3) PAIR_STAGE(cur ^ 1, tt + 1);
    const int rbase = tt * 64 + wave * 16;
    f32x4 ri[4] = {};
#pragma unroll
    for (int kc = 0; kc < 2; ++kc) {
      bf16x8 hf = *(const bf16x8*)(hib + (rbase + (lane & 15)) * 64 + kc * 32 + ((lane >> 4) << 3));
#pragma unroll
      for (int c = 0; c < 4; ++c)
        ri[c] = __builtin_amdgcn_mfma_f32_16x16x32_bf16(hf, wf[c][kc], ri[c], 0, 0, 0);
    }
#pragma unroll
    for (int r = 0; r < 4; ++r) {
      const int row = wave * 16 + ((lane >> 4) << 2) + r;
      float ss = 0.f;
#pragma unroll
      for (int c = 0; c < 4; ++c) {
        const int col = c * 16 + (lane & 15);
        float hv = bf2f(*(const unsigned short*)(Hj[cur] + (row & 63) * 128 + LDS_SWZ(row & 63, col) + ((col & 7) << 1)));
        float d = ri[c][r] - hv;
        ss += d * d;
      }
#pragma unroll
      for (int off = 1; off < 16; off <<= 1) ss += __shfl_xor(ss, off);
      if ((lane & 15) == 0) wacc += sqrtf(ss);
    }
    __syncthreads();
  }
  float tot = __shfl(wacc, 0) + __shfl(wacc, 16) + __shfl(wacc, 32) + __shfl(wacc, 48);
  if (lane == 0) red[wave] = tot;
  __syncthreads();
  if (tid == 0) dpart[blockIdx.x] = red[0] + red[1] + red[2] + red[3];
}

// ---------------- agg = sum_h w[b,h] * head_out  (weights computed inline) ----------------
__global__ __launch_bounds__(256) void k_agg(const unsigned short* __restrict__ hob,
                                             const float* __restrict__ dpart,
                                             const float* __restrict__ scal,
                                             unsigned short* __restrict__ aggb) {
  __shared__ float sc_s[2][28];
  __shared__ float filt[2][8];
  __shared__ float wts_s[16];
  const int tid = threadIdx.x;
  if (tid < 56) {
    int bb = tid / 28, pp = tid % 28;
    int base = (bb * 28 + pp) * 8;
    float diff = 0.f;
#pragma unroll
    for (int c = 0; c < 8; ++c) diff += dpart[base + c];
    diff /= 2048.f;
    sc_s[bb][pp] = expf(-diff * scal[0] / 0.1f);
  }
  __syncthreads();
  if (tid < 16) {
    int bb = tid / 8, h = tid % 8;
    float cons = 0.f;
    for (int h2 = 0; h2 < 8; ++h2)
      if (h2 != h) {
        int i_ = h < h2 ? h : h2, j_ = h < h2 ? h2 : h;
        int pp = i_ * (15 - i_) / 2 + (j_ - i_ - 1);
        cons += sc_s[bb][pp];
      }
    cons /= 7.f;
    filt[bb][h] = (cons > 0.1f) ? cons : 0.f;
  }
  __syncthreads();
  if (tid < 16) {
    int bb = tid / 8, h = tid % 8;
    float m = -1e30f;
    for (int h2 = 0; h2 < 8; ++h2) m = fmaxf(m, filt[bb][h2] + 1e-10f);
    float s = 0.f;
    for (int h2 = 0; h2 < 8; ++h2) s += expf(filt[bb][h2] + 1e-10f - m);
    wts_s[tid] = expf(filt[bb][h] + 1e-10f - m) / s;
  }
  __syncthreads();
  int t = blockIdx.x * blockDim.x + tid;
  if (t >= 4096 * 8) return;
  int r = t >> 3, dblk = t & 7;
  int b = r >> 11, n = r & 2047;
  float acc[8] = {};
#pragma unroll
  for (int h = 0; h < 8; ++h) {
    float w = wts_s[b * 8 + h];
    bf16x8 v = *(const bf16x8*)(hob + (((b * 8 + h) << 11) + n) * 64 + dblk * 8);
#pragma unroll
    for (int e = 0; e < 8; ++e) acc[e] += w * bf2f((unsigned short)v[e]);
  }
  bf16x8 o;
#pragma unroll
  for (int e = 0; e < 8; ++e) o[e] = (short)f2bf(acc[e]);
  *(bf16x8*)(aggb + r * 64 + dblk * 8) = o;
}

// ---------------- final: out = agg @ Wsum^T + bo (K=64) ----------------
__global__ __launch_bounds__(256) void k_out(const unsigned short* __restrict__ aggb,
                                             const unsigned short* __restrict__ wsb,
                                             const float* __restrict__ bo,
                                             float* __restrict__ out) {
  __shared__ alignas(16) unsigned char Ws[64 * 128];
  const int tid = threadIdx.x, wave = tid >> 6, lane = tid & 63;
  const int rowb = blockIdx.x * 64, colb = blockIdx.y * 64;
#pragma unroll
  for (int is = 0; is < 2; ++is) {
    const int L = is * 256 + tid;
    const int row = L >> 3, pos = L & 7;
    gld_lds16(wsb + (colb + row) * 64 + ((pos ^ (row & 7)) << 3), Ws + (is * 256 + wave * 64) * 16);
  }
  __syncthreads();
  bf16x8 af[2];
#pragma unroll
  for (int kc = 0; kc < 2; ++kc)
    af[kc] = *(const bf16x8*)(aggb + (rowb + wave * 16 + (lane & 15)) * 64 + kc * 32 + ((lane >> 4) << 3));
  f32x4 acc[4] = {};
#pragma unroll
  for (int c = 0; c < 4; ++c)
#pragma unroll
    for (int kc = 0; kc < 2; ++kc) {
      const int row = c * 16 + (lane & 15);
      const int col = kc * 32 + ((lane >> 4) << 3);
      bf16x8 wfr = *(const bf16x8*)(Ws + row * 128 + LDS_SWZ(row, col));
      acc[c] = __builtin_amdgcn_mfma_f32_16x16x32_bf16(af[kc], wfr, acc[c], 0, 0, 0);
    }
#pragma unroll
  for (int c = 0; c < 4; ++c)
#pragma unroll
    for (int r = 0; r < 4; ++r) {
      const int grow = rowb + wave * 16 + ((lane >> 4) << 2) + r;
      const int col = colb + c * 16 + (lane & 15);
      out[grow * 512 + col] = acc[c][r] + bo[col];
    }
}

extern "C" void kernel_launch(void* const* d_in, const int* in_sizes, int n_in,
                              void* d_out, int out_size, void* d_ws, size_t ws_size,
                              hipStream_t stream) {
  const float* x  = (const float*)d_in[0];
  const float* Wq = (const float*)d_in[1];
  const float* bq = (const float*)d_in[2];
  const float* Wk = (const float*)d_in[3];
  const float* bk = (const float*)d_in[4];
  const float* Wv = (const float*)d_in[5];
  const float* bv = (const float*)d_in[6];
  const float* Wo = (const float*)d_in[7];
  const float* bo = (const float*)d_in[8];
  const float* Wr = (const float*)d_in[9];
  const float* ascale = (const float*)d_in[10];
  float* out = (float*)d_out;

  // R2-proven layout: every big buffer at 4MB spacing.
  char* ws = (char*)d_ws;
  unsigned short* xb   = (unsigned short*)(ws);                          // 4096x512 bf16 (4MB)
  unsigned short* qb   = (unsigned short*)(ws + (4u << 20));             // [bh][n][dh] (4MB)
  unsigned short* kb   = (unsigned short*)(ws + (8u << 20));             // [bh][n][dh] (4MB)
  unsigned short* vtb  = (unsigned short*)(ws + (12u << 20));            // [bh][dh][n] (4MB)
  unsigned short* hob  = (unsigned short*)(ws + (16u << 20));            // [bh][n][dh] (4MB)
  unsigned short* wb   = (unsigned short*)(ws + (20u << 20));            // 3x512x512 (1.5MB)
  unsigned short* wrb  = (unsigned short*)(ws + (20u << 20) + 3u * 512 * 512 * 2);
  unsigned short* wsb  = (unsigned short*)(ws + (20u << 20) + 3u * 512 * 512 * 2 + 28u * 64 * 64 * 2);
  unsigned short* aggb = (unsigned short*)(ws + (22u << 20));            // 4096x64 (512KB)
  float* dpart = (float*)(ws + (23u << 20));                             // 448 floats

  k_prep<<<3056, 256, 0, stream>>>(x, Wq, Wk, Wv, Wr, Wo, xb, wb, wrb, wsb);
  k_qkv<<<dim3(32, 8, 3), 256, 0, stream>>>(xb, wb, bq, bk, bv, qb, kb, vtb);
  k_attn<<<512, 512, 0, stream>>>(qb, kb, vtb, hob);
  k_pair<<<448, 256, 0, stream>>>(hob, wrb, dpart);
  k_agg<<<128, 256, 0, stream>>>(hob, dpart, ascale, aggb);
  k_out<<<dim3(64, 8), 256, 0, stream>>>(aggb, wsb, bo, out);
}